// Round 1
// baseline (2055.112 us; speedup 1.0000x reference)
//
#include <hip/hip_runtime.h>
#include <math.h>

#define MBS   64
#define QLENS 20
#define EMBS  32
#define QVSS  128
#define ANSS  10
#define CHS   24
#define NOBJS 64
#define GS    256

typedef __attribute__((ext_vector_type(8))) short short8;
typedef __attribute__((ext_vector_type(4))) float f32x4;

__device__ __forceinline__ unsigned short f2bf(float f) {
  unsigned u = __float_as_uint(f);
  u += 0x7fffu + ((u >> 16) & 1u);
  return (unsigned short)(u >> 16);
}
__device__ __forceinline__ float sigm(float x) { return 1.0f / (1.0f + expf(-x)); }

// ---------------- weight prep: f32 -> bf16 for g2/g3/g4 ----------------
__global__ __launch_bounds__(256) void wprep_k(const float* __restrict__ g2w,
                                               const float* __restrict__ g3w,
                                               const float* __restrict__ g4w,
                                               unsigned short* __restrict__ wbf) {
  int idx = blockIdx.x * 256 + threadIdx.x;          // 3*65536
  int l = idx >> 16, r = idx & 65535;
  const float* src = (l == 0) ? g2w : ((l == 1) ? g3w : g4w);
  wbf[idx] = f2bf(src[r]);
}

// ---------------- embed + input projection for LSTM ----------------
// xproj[(t*64+b)*512+gt] = bih[gt]+bhh[gt] + dot(wih[gt,:32], emb[question[b,t],:])
__global__ __launch_bounds__(256) void xproj_k(const int* __restrict__ question,
                                               const float* __restrict__ emb,
                                               const float* __restrict__ wih,
                                               const float* __restrict__ bih,
                                               const float* __restrict__ bhh,
                                               float* __restrict__ xproj) {
  int idx = blockIdx.x * 256 + threadIdx.x;          // 20*64*512
  int gt = idx & 511;
  int b  = (idx >> 9) & 63;
  int t  = idx >> 15;
  int tok = question[b * QLENS + t];
  const float* e  = emb + tok * EMBS;
  const float* wr = wih + gt * EMBS;
  float acc = bih[gt] + bhh[gt];
#pragma unroll
  for (int k = 0; k < EMBS; ++k) acc += wr[k] * e[k];
  xproj[idx] = acc;
}

// ---------------- sequential LSTM, one block per batch element ----------------
__global__ __launch_bounds__(512) void lstm_k(const float* __restrict__ xproj,
                                              const float* __restrict__ whh,
                                              float* __restrict__ qvec) {
  int b = blockIdx.x;
  int gt = threadIdx.x;                               // 0..511
  __shared__ float h[QVSS];
  __shared__ float gates[4 * QVSS];
  float w[QVSS];
#pragma unroll
  for (int k = 0; k < QVSS; ++k) w[k] = whh[gt * QVSS + k];
  float c = 0.0f;
  if (gt < QVSS) h[gt] = 0.0f;
  __syncthreads();
  for (int t = 0; t < QLENS; ++t) {
    float acc = xproj[(t * MBS + b) * 512 + gt];
#pragma unroll
    for (int k = 0; k < QVSS; ++k) acc += w[k] * h[k];
    gates[gt] = acc;
    __syncthreads();
    if (gt < QVSS) {
      float ig = gates[gt];
      float fg = gates[QVSS + gt];
      float gg = gates[2 * QVSS + gt];
      float og = gates[3 * QVSS + gt];
      c = sigm(fg) * c + sigm(ig) * tanhf(gg);
      h[gt] = sigm(og) * tanhf(c);
    }
    __syncthreads();
  }
  if (gt < QVSS) qvec[b * QVSS + gt] = h[gt];
}

// ---------------- direct conv (stride2 pad1 3x3) + BN-stat atomics ----------------
template <int CIN, int H>
__global__ __launch_bounds__(256) void conv_k(const float* __restrict__ x,
                                              const float* __restrict__ w,
                                              const float* __restrict__ bias,
                                              float* __restrict__ y,
                                              float* __restrict__ st) {
  const int OH = H / 2;
  __shared__ float sw[CIN * CHS * 9];
  __shared__ float sb[CHS];
  for (int i = threadIdx.x; i < CIN * CHS * 9; i += 256) sw[i] = w[i];
  if (threadIdx.x < CHS) sb[threadIdx.x] = bias[threadIdx.x];
  __syncthreads();
  int idx = blockIdx.x * 256 + threadIdx.x;           // 64*24*OH*OH, exact grid
  int ow = idx % OH;
  int oh = (idx / OH) % OH;
  int co = (idx / (OH * OH)) % CHS;
  int b  = idx / (CHS * OH * OH);
  float acc = sb[co];
  const float* xb = x + b * CIN * H * H;
#pragma unroll
  for (int kh = 0; kh < 3; ++kh) {
    int ih = oh * 2 - 1 + kh;
    if (ih < 0 || ih >= H) continue;
#pragma unroll
    for (int kw = 0; kw < 3; ++kw) {
      int iw = ow * 2 - 1 + kw;
      if (iw < 0 || iw >= H) continue;
      for (int ci = 0; ci < CIN; ++ci)
        acc += xb[(ci * H + ih) * H + iw] * sw[(co * CIN + ci) * 9 + kh * 3 + kw];
    }
  }
  y[idx] = acc;
  // per-wave BN partial stats (channel is wave-uniform: OH*OH multiple of 64)
  float s = acc, s2 = acc * acc;
#pragma unroll
  for (int off = 1; off < 64; off <<= 1) {
    s  += __shfl_xor(s, off);
    s2 += __shfl_xor(s2, off);
  }
  if ((threadIdx.x & 63) == 0) {
    atomicAdd(&st[co * 2 + 0], s);
    atomicAdd(&st[co * 2 + 1], s2);
  }
}

// ---------------- BN apply + relu, in place ----------------
__global__ __launch_bounds__(256) void bn_k(float* __restrict__ y,
                                            const float* __restrict__ st,
                                            const float* __restrict__ g,
                                            const float* __restrict__ beta,
                                            int HW, float inv_cnt) {
  int idx = blockIdx.x * 256 + threadIdx.x;
  int co = (idx / HW) % CHS;
  float m = st[co * 2 + 0] * inv_cnt;
  float v = st[co * 2 + 1] * inv_cnt - m * m;
  float r = rsqrtf(v + 1e-5f);
  float val = (y[idx] - m) * r * g[co] + beta[co];
  y[idx] = fmaxf(val, 0.0f);
}

// ---------------- object projections: pre_i / pre_j ----------------
__global__ __launch_bounds__(256) void preobj_k(const float* __restrict__ x4,
                                                const float* __restrict__ g1w,
                                                float* __restrict__ pre_i,
                                                float* __restrict__ pre_j) {
  int bo = blockIdx.x;                                // 64*64
  int b = bo >> 6, o = bo & 63;
  int n = threadIdx.x;                                // 256
  __shared__ float obj[32];
  if (n < CHS) obj[n] = x4[(b * CHS + n) * NOBJS + o];
  if (n == 24) obj[24] = (float)(o / 8 - 2) * 0.5f;
  if (n == 25) obj[25] = (float)(o % 8 - 2) * 0.5f;
  __syncthreads();
  const float* wr = g1w + n * 180;
  float ai = 0.0f, aj = 0.0f;
#pragma unroll
  for (int f = 0; f < 26; ++f) {
    ai += wr[f] * obj[f];
    aj += wr[26 + f] * obj[f];
  }
  pre_i[bo * GS + n] = ai;
  pre_j[bo * GS + n] = aj;
}

// ---------------- question projection: pre_q (includes g1_b) ----------------
__global__ __launch_bounds__(256) void preq_k(const float* __restrict__ qvec,
                                              const float* __restrict__ g1w,
                                              const float* __restrict__ g1b,
                                              float* __restrict__ pre_q) {
  int b = blockIdx.x;
  int n = threadIdx.x;
  __shared__ float q[QVSS];
  if (n < QVSS) q[n] = qvec[b * QVSS + n];
  __syncthreads();
  const float* wr = g1w + n * 180 + 52;
  float a = g1b[n];
#pragma unroll
  for (int k = 0; k < QVSS; ++k) a += wr[k] * q[k];
  pre_q[b * GS + n] = a;
}

// ---------------- the big fused relational MLP (MFMA bf16) ----------------
// block = (b, j): 64 relation rows (i) x 256 feats; 3 layers fused in LDS.
__global__ __launch_bounds__(256) void rel_k(const float* __restrict__ pre_i,
                                             const float* __restrict__ pre_j,
                                             const float* __restrict__ pre_q,
                                             const unsigned short* __restrict__ wbf,
                                             const float* __restrict__ g2b,
                                             const float* __restrict__ g3b,
                                             const float* __restrict__ g4b,
                                             float* __restrict__ xg) {
  __shared__ short8 hbv[2][2048];                     // 2 x 64x256 bf16, swizzled
  unsigned short* hbs0 = (unsigned short*)&hbv[0][0];
  unsigned short* hbs1 = (unsigned short*)&hbv[1][0];
  int bid = blockIdx.x;
  int b = bid >> 6, j = bid & 63;
  int tid = threadIdx.x;
  int w = tid >> 6, lane = tid & 63;
  const int ln = lane & 15, lq = lane >> 4;

  // phase 0: h0 = relu(pre_j[b,j] + pre_i[b,i] + pre_q[b]) -> hbv[0] (bf16, swizzled)
  {
    int r = tid >> 2, kq = tid & 3;
    const float* pj = pre_j + (b * 64 + j) * GS;
    const float* pi = pre_i + (b * 64 + r) * GS;
    const float* pq = pre_q + b * GS;
    for (int kk = 0; kk < 64; kk += 8) {
      int k0 = kq * 64 + kk;
      short8 pack;
#pragma unroll
      for (int e = 0; e < 8; ++e) {
        int k = k0 + e;
        float v = pj[k] + pi[k] + pq[k];
        pack[e] = (short)f2bf(fmaxf(v, 0.0f));
      }
      int idx8 = ((r << 5) + (k0 >> 3)) ^ (r & 7);
      hbv[0][idx8] = pack;
    }
  }

  int cur = 0;
  const short8* Wv = (const short8*)wbf;
#pragma unroll 1
  for (int L = 0; L < 3; ++L) {
    __syncthreads();
    const float* bias = (L == 0) ? g2b : ((L == 1) ? g3b : g4b);
    const short8* WL = Wv + L * 8192;                 // 65536/8 per layer
    f32x4 acc[4][4];
#pragma unroll
    for (int ci = 0; ci < 4; ++ci)
#pragma unroll
      for (int rt = 0; rt < 4; ++rt) acc[ci][rt] = (f32x4){0.f, 0.f, 0.f, 0.f};

#pragma unroll
    for (int ci = 0; ci < 4; ++ci) {
      int n = (w * 4 + ci) * 16 + ln;
      short8 bf[8];
#pragma unroll
      for (int kt = 0; kt < 8; ++kt) bf[kt] = WL[n * 32 + kt * 4 + lq];
#pragma unroll
      for (int rt = 0; rt < 4; ++rt) {
        int r = rt * 16 + ln;
#pragma unroll
        for (int kt = 0; kt < 8; ++kt) {
          int idx8 = ((r << 5) + (kt << 2) + lq) ^ (r & 7);
          short8 af = hbv[cur][idx8];
          acc[ci][rt] = __builtin_amdgcn_mfma_f32_16x16x32_bf16(af, bf[kt], acc[ci][rt], 0, 0, 0);
        }
      }
    }

    if (L < 2) {
      unsigned short* dst = (cur ? hbs0 : hbs1);
#pragma unroll
      for (int ci = 0; ci < 4; ++ci) {
        int n = (w * 4 + ci) * 16 + ln;
        float bn = bias[n];
#pragma unroll
        for (int rt = 0; rt < 4; ++rt) {
#pragma unroll
          for (int reg = 0; reg < 4; ++reg) {
            int r = rt * 16 + lq * 4 + reg;
            float v = fmaxf(acc[ci][rt][reg] + bn, 0.0f);
            dst[(r * GS + n) ^ ((r & 7) << 3)] = f2bf(v);
          }
        }
      }
      cur ^= 1;
    } else {
#pragma unroll
      for (int ci = 0; ci < 4; ++ci) {
        int ct = w * 4 + ci;
        int n = ct * 16 + ln;
        float bn = bias[n];
        float cs = 0.0f;
#pragma unroll
        for (int rt = 0; rt < 4; ++rt)
#pragma unroll
          for (int reg = 0; reg < 4; ++reg)
            cs += fmaxf(acc[ci][rt][reg] + bn, 0.0f);
        cs += __shfl_xor(cs, 16);
        cs += __shfl_xor(cs, 32);
        if (lane < 16) atomicAdd(&xg[b * GS + ct * 16 + ln], cs);
      }
    }
  }
}

// ---------------- final f-MLP + log_softmax ----------------
__global__ __launch_bounds__(256) void final_k(const float* __restrict__ xg,
                                               const float* __restrict__ f1w,
                                               const float* __restrict__ f1b,
                                               const float* __restrict__ f2w,
                                               const float* __restrict__ f2b,
                                               const float* __restrict__ f3w,
                                               const float* __restrict__ f3b,
                                               float* __restrict__ out) {
  int b = blockIdx.x, n = threadIdx.x;
  __shared__ float s0[GS], s1[GS], sl[16];
  s0[n] = xg[b * GS + n];
  __syncthreads();
  float a = f1b[n];
  for (int k = 0; k < GS; ++k) a += f1w[n * GS + k] * s0[k];
  s1[n] = fmaxf(a, 0.0f);
  __syncthreads();
  a = f2b[n];
  for (int k = 0; k < GS; ++k) a += f2w[n * GS + k] * s1[k];
  s0[n] = fmaxf(a, 0.0f);
  __syncthreads();
  if (n < ANSS) {
    a = f3b[n];
    for (int k = 0; k < GS; ++k) a += f3w[n * GS + k] * s0[k];
    sl[n] = a;
  }
  __syncthreads();
  if (n == 0) {
    float m = -1e30f;
    for (int i = 0; i < ANSS; ++i) m = fmaxf(m, sl[i]);
    float s = 0.0f;
    for (int i = 0; i < ANSS; ++i) s += expf(sl[i] - m);
    sl[12] = m + logf(s);
  }
  __syncthreads();
  if (n < ANSS) out[b * ANSS + n] = sl[n] - sl[12];
}

extern "C" void kernel_launch(void* const* d_in, const int* in_sizes, int n_in,
                              void* d_out, int out_size, void* d_ws, size_t ws_size,
                              hipStream_t stream) {
  const float* image = (const float*)d_in[0];
  const int*   question = (const int*)d_in[1];
  const float* emb = (const float*)d_in[2];
  const float* wih = (const float*)d_in[3];
  const float* whh = (const float*)d_in[4];
  const float* bih = (const float*)d_in[5];
  const float* bhh = (const float*)d_in[6];
  const float* c1w = (const float*)d_in[7];
  const float* c1b = (const float*)d_in[8];
  const float* bn1g = (const float*)d_in[9];
  const float* bn1b = (const float*)d_in[10];
  const float* c2w = (const float*)d_in[11];
  const float* c2b = (const float*)d_in[12];
  const float* bn2g = (const float*)d_in[13];
  const float* bn2b = (const float*)d_in[14];
  const float* c3w = (const float*)d_in[15];
  const float* c3b = (const float*)d_in[16];
  const float* bn3g = (const float*)d_in[17];
  const float* bn3b = (const float*)d_in[18];
  const float* c4w = (const float*)d_in[19];
  const float* c4b = (const float*)d_in[20];
  const float* bn4g = (const float*)d_in[21];
  const float* bn4b = (const float*)d_in[22];
  const float* g1w = (const float*)d_in[23];
  const float* g1b = (const float*)d_in[24];
  const float* g2w = (const float*)d_in[25];
  const float* g2b = (const float*)d_in[26];
  const float* g3w = (const float*)d_in[27];
  const float* g3b = (const float*)d_in[28];
  const float* g4w = (const float*)d_in[29];
  const float* g4b = (const float*)d_in[30];
  const float* f1w = (const float*)d_in[31];
  const float* f1b = (const float*)d_in[32];
  const float* f2w = (const float*)d_in[33];
  const float* f2b = (const float*)d_in[34];
  const float* f3w = (const float*)d_in[35];
  const float* f3b = (const float*)d_in[36];
  float* out = (float*)d_out;

  float* wsf = (float*)d_ws;
  float* arenaA = wsf;                                // 6,291,456 f  (y1/x1, y3/x3)
  float* arenaB = wsf + 6291456;                      // 1,572,864 f  (y2/x2, y4/x4)
  float* xproj  = wsf + 7864320;                      // 655,360 f
  float* qvec   = wsf + 8519680;                      // 8,192 f
  float* pre_i  = wsf + 8527872;                      // 1,048,576 f
  float* pre_j  = wsf + 9576448;                      // 1,048,576 f
  float* pre_q  = wsf + 10625024;                     // 16,384 f
  float* xg     = wsf + 10641408;                     // 16,384 f
  float* stats  = wsf + 10657792;                     // 256 f (4 layers x 24 x 2)
  unsigned short* wbf = (unsigned short*)(wsf + 10658048); // 196,608 bf16

  // zero accumulators (xg + stats are contiguous)
  hipMemsetAsync(xg, 0, (16384 + 256) * sizeof(float), stream);

  wprep_k<<<768, 256, 0, stream>>>(g2w, g3w, g4w, wbf);
  xproj_k<<<2560, 256, 0, stream>>>(question, emb, wih, bih, bhh, xproj);
  lstm_k<<<64, 512, 0, stream>>>(xproj, whh, qvec);

  conv_k<3, 128><<<24576, 256, 0, stream>>>(image, c1w, c1b, arenaA, stats + 0);
  bn_k<<<24576, 256, 0, stream>>>(arenaA, stats + 0, bn1g, bn1b, 4096, 1.0f / 262144.0f);
  conv_k<24, 64><<<6144, 256, 0, stream>>>(arenaA, c2w, c2b, arenaB, stats + 48);
  bn_k<<<6144, 256, 0, stream>>>(arenaB, stats + 48, bn2g, bn2b, 1024, 1.0f / 65536.0f);
  conv_k<24, 32><<<1536, 256, 0, stream>>>(arenaB, c3w, c3b, arenaA, stats + 96);
  bn_k<<<1536, 256, 0, stream>>>(arenaA, stats + 96, bn3g, bn3b, 256, 1.0f / 16384.0f);
  conv_k<24, 16><<<384, 256, 0, stream>>>(arenaA, c4w, c4b, arenaB, stats + 144);
  bn_k<<<384, 256, 0, stream>>>(arenaB, stats + 144, bn4g, bn4b, 64, 1.0f / 4096.0f);

  preobj_k<<<4096, 256, 0, stream>>>(arenaB, g1w, pre_i, pre_j);
  preq_k<<<64, 256, 0, stream>>>(qvec, g1w, g1b, pre_q);

  rel_k<<<4096, 256, 0, stream>>>(pre_i, pre_j, pre_q, wbf, g2b, g3b, g4b, xg);

  final_k<<<64, 256, 0, stream>>>(xg, f1w, f1b, f2w, f2b, f3w, f3b, out);
}

// Round 2
// 842.031 us; speedup vs baseline: 2.4407x; 2.4407x over previous
//
#include <hip/hip_runtime.h>
#include <math.h>

#define MBS   64
#define QLENS 20
#define EMBS  32
#define QVSS  128
#define ANSS  10
#define CHS   24
#define NOBJS 64
#define GS    256

typedef __attribute__((ext_vector_type(8))) short short8;
typedef __attribute__((ext_vector_type(4))) float f32x4;

__device__ __forceinline__ unsigned short f2bf(float f) {
  unsigned u = __float_as_uint(f);
  u += 0x7fffu + ((u >> 16) & 1u);
  return (unsigned short)(u >> 16);
}
__device__ __forceinline__ float sigm(float x) { return 1.0f / (1.0f + expf(-x)); }

// ---------------- weight prep: f32 -> bf16 for g2/g3/g4 ----------------
__global__ __launch_bounds__(256) void wprep_k(const float* __restrict__ g2w,
                                               const float* __restrict__ g3w,
                                               const float* __restrict__ g4w,
                                               unsigned short* __restrict__ wbf) {
  int idx = blockIdx.x * 256 + threadIdx.x;          // 3*65536
  int l = idx >> 16, r = idx & 65535;
  const float* src = (l == 0) ? g2w : ((l == 1) ? g3w : g4w);
  wbf[idx] = f2bf(src[r]);
}

// ---------------- embed + input projection for LSTM ----------------
__global__ __launch_bounds__(256) void xproj_k(const int* __restrict__ question,
                                               const float* __restrict__ emb,
                                               const float* __restrict__ wih,
                                               const float* __restrict__ bih,
                                               const float* __restrict__ bhh,
                                               float* __restrict__ xproj) {
  int idx = blockIdx.x * 256 + threadIdx.x;          // 20*64*512
  int gt = idx & 511;
  int b  = (idx >> 9) & 63;
  int t  = idx >> 15;
  int tok = question[b * QLENS + t];
  const float* e  = emb + tok * EMBS;
  const float* wr = wih + gt * EMBS;
  float acc = bih[gt] + bhh[gt];
#pragma unroll
  for (int k = 0; k < EMBS; ++k) acc += wr[k] * e[k];
  xproj[idx] = acc;
}

// ---------------- sequential LSTM, one block per batch element ----------------
__global__ __launch_bounds__(512) void lstm_k(const float* __restrict__ xproj,
                                              const float* __restrict__ whh,
                                              float* __restrict__ qvec) {
  int b = blockIdx.x;
  int gt = threadIdx.x;                               // 0..511
  __shared__ float h[QVSS];
  __shared__ float gates[4 * QVSS];
  float w[QVSS];
#pragma unroll
  for (int k = 0; k < QVSS; ++k) w[k] = whh[gt * QVSS + k];
  float c = 0.0f;
  if (gt < QVSS) h[gt] = 0.0f;
  __syncthreads();
  for (int t = 0; t < QLENS; ++t) {
    float acc = xproj[(t * MBS + b) * 512 + gt];
#pragma unroll
    for (int k = 0; k < QVSS; ++k) acc += w[k] * h[k];
    gates[gt] = acc;
    __syncthreads();
    if (gt < QVSS) {
      float ig = gates[gt];
      float fg = gates[QVSS + gt];
      float gg = gates[2 * QVSS + gt];
      float og = gates[3 * QVSS + gt];
      c = sigm(fg) * c + sigm(ig) * tanhf(gg);
      h[gt] = sigm(og) * tanhf(c);
    }
    __syncthreads();
  }
  if (gt < QVSS) qvec[b * QVSS + gt] = h[gt];
}

// ---------------- direct conv (stride2 pad1 3x3), pure ----------------
template <int CIN, int H>
__global__ __launch_bounds__(256) void conv_k(const float* __restrict__ x,
                                              const float* __restrict__ w,
                                              const float* __restrict__ bias,
                                              float* __restrict__ y) {
  const int OH = H / 2;
  __shared__ float sw[CIN * CHS * 9];
  __shared__ float sb[CHS];
  for (int i = threadIdx.x; i < CIN * CHS * 9; i += 256) sw[i] = w[i];
  if (threadIdx.x < CHS) sb[threadIdx.x] = bias[threadIdx.x];
  __syncthreads();
  int idx = blockIdx.x * 256 + threadIdx.x;           // 64*24*OH*OH, exact grid
  int ow = idx % OH;
  int oh = (idx / OH) % OH;
  int co = (idx / (OH * OH)) % CHS;
  int b  = idx / (CHS * OH * OH);
  float acc = sb[co];
  const float* xb = x + b * CIN * H * H;
#pragma unroll
  for (int kh = 0; kh < 3; ++kh) {
    int ih = oh * 2 - 1 + kh;
    if (ih < 0 || ih >= H) continue;
#pragma unroll
    for (int kw = 0; kw < 3; ++kw) {
      int iw = ow * 2 - 1 + kw;
      if (iw < 0 || iw >= H) continue;
      for (int ci = 0; ci < CIN; ++ci)
        acc += xb[(ci * H + ih) * H + iw] * sw[(co * CIN + ci) * 9 + kh * 3 + kw];
    }
  }
  y[idx] = acc;
}

// ---------------- BN stats: per (channel, sub-range) block, few atomics ----------------
__global__ __launch_bounds__(256) void stats_k(const float* __restrict__ y,
                                               float* __restrict__ st,
                                               int HW, int SUB) {
  int c = blockIdx.x / SUB, sub = blockIdx.x % SUB;
  int bpb = MBS / SUB;
  float s = 0.0f, s2 = 0.0f;
  for (int b = sub * bpb; b < (sub + 1) * bpb; ++b) {
    const float* p = y + (b * CHS + c) * HW;
    for (int i = threadIdx.x * 4; i < HW; i += 1024) {
      float4 v = *reinterpret_cast<const float4*>(p + i);
      s  += v.x + v.y + v.z + v.w;
      s2 += v.x * v.x + v.y * v.y + v.z * v.z + v.w * v.w;
    }
  }
#pragma unroll
  for (int off = 1; off < 64; off <<= 1) {
    s  += __shfl_xor(s, off);
    s2 += __shfl_xor(s2, off);
  }
  __shared__ float rs[4], rs2[4];
  int w = threadIdx.x >> 6;
  if ((threadIdx.x & 63) == 0) { rs[w] = s; rs2[w] = s2; }
  __syncthreads();
  if (threadIdx.x == 0) {
    atomicAdd(&st[c * 2 + 0], rs[0] + rs[1] + rs[2] + rs[3]);
    atomicAdd(&st[c * 2 + 1], rs2[0] + rs2[1] + rs2[2] + rs2[3]);
  }
}

// ---------------- BN apply + relu, in place ----------------
__global__ __launch_bounds__(256) void bn_k(float* __restrict__ y,
                                            const float* __restrict__ st,
                                            const float* __restrict__ g,
                                            const float* __restrict__ beta,
                                            int HW, float inv_cnt) {
  int idx = blockIdx.x * 256 + threadIdx.x;
  int co = (idx / HW) % CHS;
  float m = st[co * 2 + 0] * inv_cnt;
  float v = st[co * 2 + 1] * inv_cnt - m * m;
  float r = rsqrtf(v + 1e-5f);
  float val = (y[idx] - m) * r * g[co] + beta[co];
  y[idx] = fmaxf(val, 0.0f);
}

// ---------------- object projections: pre_i / pre_j ----------------
__global__ __launch_bounds__(256) void preobj_k(const float* __restrict__ x4,
                                                const float* __restrict__ g1w,
                                                float* __restrict__ pre_i,
                                                float* __restrict__ pre_j) {
  int bo = blockIdx.x;                                // 64*64
  int b = bo >> 6, o = bo & 63;
  int n = threadIdx.x;                                // 256
  __shared__ float obj[32];
  if (n < CHS) obj[n] = x4[(b * CHS + n) * NOBJS + o];
  if (n == 24) obj[24] = (float)(o / 8 - 2) * 0.5f;
  if (n == 25) obj[25] = (float)(o % 8 - 2) * 0.5f;
  __syncthreads();
  const float* wr = g1w + n * 180;
  float ai = 0.0f, aj = 0.0f;
#pragma unroll
  for (int f = 0; f < 26; ++f) {
    ai += wr[f] * obj[f];
    aj += wr[26 + f] * obj[f];
  }
  pre_i[bo * GS + n] = ai;
  pre_j[bo * GS + n] = aj;
}

// ---------------- question projection: pre_q (includes g1_b) ----------------
__global__ __launch_bounds__(256) void preq_k(const float* __restrict__ qvec,
                                              const float* __restrict__ g1w,
                                              const float* __restrict__ g1b,
                                              float* __restrict__ pre_q) {
  int b = blockIdx.x;
  int n = threadIdx.x;
  __shared__ float q[QVSS];
  if (n < QVSS) q[n] = qvec[b * QVSS + n];
  __syncthreads();
  const float* wr = g1w + n * 180 + 52;
  float a = g1b[n];
#pragma unroll
  for (int k = 0; k < QVSS; ++k) a += wr[k] * q[k];
  pre_q[b * GS + n] = a;
}

// ---------------- the big fused relational MLP (MFMA bf16) ----------------
__global__ __launch_bounds__(256) void rel_k(const float* __restrict__ pre_i,
                                             const float* __restrict__ pre_j,
                                             const float* __restrict__ pre_q,
                                             const unsigned short* __restrict__ wbf,
                                             const float* __restrict__ g2b,
                                             const float* __restrict__ g3b,
                                             const float* __restrict__ g4b,
                                             float* __restrict__ xg) {
  __shared__ short8 hbv[2][2048];                     // 2 x 64x256 bf16, swizzled
  unsigned short* hbs0 = (unsigned short*)&hbv[0][0];
  unsigned short* hbs1 = (unsigned short*)&hbv[1][0];
  int bid = blockIdx.x;
  int b = bid >> 6, j = bid & 63;
  int tid = threadIdx.x;
  int w = tid >> 6, lane = tid & 63;
  const int ln = lane & 15, lq = lane >> 4;

  // phase 0: h0 = relu(pre_j[b,j] + pre_i[b,i] + pre_q[b]) -> hbv[0] (bf16, swizzled)
  {
    int r = tid >> 2, kq = tid & 3;
    const float* pj = pre_j + (b * 64 + j) * GS;
    const float* pi = pre_i + (b * 64 + r) * GS;
    const float* pq = pre_q + b * GS;
    for (int kk = 0; kk < 64; kk += 8) {
      int k0 = kq * 64 + kk;
      short8 pack;
#pragma unroll
      for (int e = 0; e < 8; ++e) {
        int k = k0 + e;
        float v = pj[k] + pi[k] + pq[k];
        pack[e] = (short)f2bf(fmaxf(v, 0.0f));
      }
      int idx8 = ((r << 5) + (k0 >> 3)) ^ (r & 7);
      hbv[0][idx8] = pack;
    }
  }

  int cur = 0;
  const short8* Wv = (const short8*)wbf;
#pragma unroll 1
  for (int L = 0; L < 3; ++L) {
    __syncthreads();
    const float* bias = (L == 0) ? g2b : ((L == 1) ? g3b : g4b);
    const short8* WL = Wv + L * 8192;                 // 65536/8 per layer
    f32x4 acc[4][4];
#pragma unroll
    for (int ci = 0; ci < 4; ++ci)
#pragma unroll
      for (int rt = 0; rt < 4; ++rt) acc[ci][rt] = (f32x4){0.f, 0.f, 0.f, 0.f};

#pragma unroll
    for (int ci = 0; ci < 4; ++ci) {
      int n = (w * 4 + ci) * 16 + ln;
      short8 bf[8];
#pragma unroll
      for (int kt = 0; kt < 8; ++kt) bf[kt] = WL[n * 32 + kt * 4 + lq];
#pragma unroll
      for (int rt = 0; rt < 4; ++rt) {
        int r = rt * 16 + ln;
#pragma unroll
        for (int kt = 0; kt < 8; ++kt) {
          int idx8 = ((r << 5) + (kt << 2) + lq) ^ (r & 7);
          short8 af = hbv[cur][idx8];
          acc[ci][rt] = __builtin_amdgcn_mfma_f32_16x16x32_bf16(af, bf[kt], acc[ci][rt], 0, 0, 0);
        }
      }
    }

    if (L < 2) {
      unsigned short* dst = (cur ? hbs0 : hbs1);
#pragma unroll
      for (int ci = 0; ci < 4; ++ci) {
        int n = (w * 4 + ci) * 16 + ln;
        float bn = bias[n];
#pragma unroll
        for (int rt = 0; rt < 4; ++rt) {
#pragma unroll
          for (int reg = 0; reg < 4; ++reg) {
            int r = rt * 16 + lq * 4 + reg;
            float v = fmaxf(acc[ci][rt][reg] + bn, 0.0f);
            dst[(r * GS + n) ^ ((r & 7) << 3)] = f2bf(v);
          }
        }
      }
      cur ^= 1;
    } else {
#pragma unroll
      for (int ci = 0; ci < 4; ++ci) {
        int ct = w * 4 + ci;
        int n = ct * 16 + ln;
        float bn = bias[n];
        float cs = 0.0f;
#pragma unroll
        for (int rt = 0; rt < 4; ++rt)
#pragma unroll
          for (int reg = 0; reg < 4; ++reg)
            cs += fmaxf(acc[ci][rt][reg] + bn, 0.0f);
        cs += __shfl_xor(cs, 16);
        cs += __shfl_xor(cs, 32);
        if (lane < 16) atomicAdd(&xg[b * GS + ct * 16 + ln], cs);
      }
    }
  }
}

// ---------------- final f-MLP + log_softmax ----------------
__global__ __launch_bounds__(256) void final_k(const float* __restrict__ xg,
                                               const float* __restrict__ f1w,
                                               const float* __restrict__ f1b,
                                               const float* __restrict__ f2w,
                                               const float* __restrict__ f2b,
                                               const float* __restrict__ f3w,
                                               const float* __restrict__ f3b,
                                               float* __restrict__ out) {
  int b = blockIdx.x, n = threadIdx.x;
  __shared__ float s0[GS], s1[GS], sl[16];
  s0[n] = xg[b * GS + n];
  __syncthreads();
  float a = f1b[n];
  for (int k = 0; k < GS; ++k) a += f1w[n * GS + k] * s0[k];
  s1[n] = fmaxf(a, 0.0f);
  __syncthreads();
  a = f2b[n];
  for (int k = 0; k < GS; ++k) a += f2w[n * GS + k] * s1[k];
  s0[n] = fmaxf(a, 0.0f);
  __syncthreads();
  if (n < ANSS) {
    a = f3b[n];
    for (int k = 0; k < GS; ++k) a += f3w[n * GS + k] * s0[k];
    sl[n] = a;
  }
  __syncthreads();
  if (n == 0) {
    float m = -1e30f;
    for (int i = 0; i < ANSS; ++i) m = fmaxf(m, sl[i]);
    float s = 0.0f;
    for (int i = 0; i < ANSS; ++i) s += expf(sl[i] - m);
    sl[12] = m + logf(s);
  }
  __syncthreads();
  if (n < ANSS) out[b * ANSS + n] = sl[n] - sl[12];
}

extern "C" void kernel_launch(void* const* d_in, const int* in_sizes, int n_in,
                              void* d_out, int out_size, void* d_ws, size_t ws_size,
                              hipStream_t stream) {
  const float* image = (const float*)d_in[0];
  const int*   question = (const int*)d_in[1];
  const float* emb = (const float*)d_in[2];
  const float* wih = (const float*)d_in[3];
  const float* whh = (const float*)d_in[4];
  const float* bih = (const float*)d_in[5];
  const float* bhh = (const float*)d_in[6];
  const float* c1w = (const float*)d_in[7];
  const float* c1b = (const float*)d_in[8];
  const float* bn1g = (const float*)d_in[9];
  const float* bn1b = (const float*)d_in[10];
  const float* c2w = (const float*)d_in[11];
  const float* c2b = (const float*)d_in[12];
  const float* bn2g = (const float*)d_in[13];
  const float* bn2b = (const float*)d_in[14];
  const float* c3w = (const float*)d_in[15];
  const float* c3b = (const float*)d_in[16];
  const float* bn3g = (const float*)d_in[17];
  const float* bn3b = (const float*)d_in[18];
  const float* c4w = (const float*)d_in[19];
  const float* c4b = (const float*)d_in[20];
  const float* bn4g = (const float*)d_in[21];
  const float* bn4b = (const float*)d_in[22];
  const float* g1w = (const float*)d_in[23];
  const float* g1b = (const float*)d_in[24];
  const float* g2w = (const float*)d_in[25];
  const float* g2b = (const float*)d_in[26];
  const float* g3w = (const float*)d_in[27];
  const float* g3b = (const float*)d_in[28];
  const float* g4w = (const float*)d_in[29];
  const float* g4b = (const float*)d_in[30];
  const float* f1w = (const float*)d_in[31];
  const float* f1b = (const float*)d_in[32];
  const float* f2w = (const float*)d_in[33];
  const float* f2b = (const float*)d_in[34];
  const float* f3w = (const float*)d_in[35];
  const float* f3b = (const float*)d_in[36];
  float* out = (float*)d_out;

  float* wsf = (float*)d_ws;
  float* arenaA = wsf;                                // 6,291,456 f
  float* arenaB = wsf + 6291456;                      // 1,572,864 f
  float* xproj  = wsf + 7864320;                      // 655,360 f
  float* qvec   = wsf + 8519680;                      // 8,192 f
  float* pre_i  = wsf + 8527872;                      // 1,048,576 f
  float* pre_j  = wsf + 9576448;                      // 1,048,576 f
  float* pre_q  = wsf + 10625024;                     // 16,384 f
  float* xg     = wsf + 10641408;                     // 16,384 f
  float* stats  = wsf + 10657792;                     // 256 f (4 layers x 24 x 2)
  unsigned short* wbf = (unsigned short*)(wsf + 10658048); // 196,608 bf16

  hipMemsetAsync(xg, 0, (16384 + 256) * sizeof(float), stream);

  wprep_k<<<768, 256, 0, stream>>>(g2w, g3w, g4w, wbf);
  xproj_k<<<2560, 256, 0, stream>>>(question, emb, wih, bih, bhh, xproj);
  lstm_k<<<64, 512, 0, stream>>>(xproj, whh, qvec);

  conv_k<3, 128><<<24576, 256, 0, stream>>>(image, c1w, c1b, arenaA);
  stats_k<<<24 * 16, 256, 0, stream>>>(arenaA, stats + 0, 4096, 16);
  bn_k<<<24576, 256, 0, stream>>>(arenaA, stats + 0, bn1g, bn1b, 4096, 1.0f / 262144.0f);

  conv_k<24, 64><<<6144, 256, 0, stream>>>(arenaA, c2w, c2b, arenaB);
  stats_k<<<24 * 16, 256, 0, stream>>>(arenaB, stats + 48, 1024, 16);
  bn_k<<<6144, 256, 0, stream>>>(arenaB, stats + 48, bn2g, bn2b, 1024, 1.0f / 65536.0f);

  conv_k<24, 32><<<1536, 256, 0, stream>>>(arenaB, c3w, c3b, arenaA);
  stats_k<<<24 * 4, 256, 0, stream>>>(arenaA, stats + 96, 256, 4);
  bn_k<<<1536, 256, 0, stream>>>(arenaA, stats + 96, bn3g, bn3b, 256, 1.0f / 16384.0f);

  conv_k<24, 16><<<384, 256, 0, stream>>>(arenaA, c4w, c4b, arenaB);
  stats_k<<<24, 256, 0, stream>>>(arenaB, stats + 144, 64, 1);
  bn_k<<<384, 256, 0, stream>>>(arenaB, stats + 144, bn4g, bn4b, 64, 1.0f / 4096.0f);

  preobj_k<<<4096, 256, 0, stream>>>(arenaB, g1w, pre_i, pre_j);
  preq_k<<<64, 256, 0, stream>>>(qvec, g1w, g1b, pre_q);

  rel_k<<<4096, 256, 0, stream>>>(pre_i, pre_j, pre_q, wbf, g2b, g3b, g4b, xg);

  final_k<<<64, 256, 0, stream>>>(xg, f1w, f1b, f2w, f2b, f3w, f3b, out);
}

// Round 3
// 776.347 us; speedup vs baseline: 2.6472x; 1.0846x over previous
//
#include <hip/hip_runtime.h>
#include <math.h>

#define MBS   64
#define QLENS 20
#define EMBS  32
#define QVSS  128
#define ANSS  10
#define CHS   24
#define NOBJS 64
#define GS    256

typedef __attribute__((ext_vector_type(8))) short short8;
typedef __attribute__((ext_vector_type(4))) float f32x4;
typedef __attribute__((ext_vector_type(16))) float f32x16;

__device__ __forceinline__ unsigned short f2bf(float f) {
  unsigned u = __float_as_uint(f);
  u += 0x7fffu + ((u >> 16) & 1u);
  return (unsigned short)(u >> 16);
}
__device__ __forceinline__ float sigm(float x) { return 1.0f / (1.0f + expf(-x)); }

// ---------------- weight prep: f32 -> bf16 for g2/g3/g4 ----------------
__global__ __launch_bounds__(256) void wprep_k(const float* __restrict__ g2w,
                                               const float* __restrict__ g3w,
                                               const float* __restrict__ g4w,
                                               unsigned short* __restrict__ wbf) {
  int idx = blockIdx.x * 256 + threadIdx.x;          // 3*65536
  int l = idx >> 16, r = idx & 65535;
  const float* src = (l == 0) ? g2w : ((l == 1) ? g3w : g4w);
  wbf[idx] = f2bf(src[r]);
}

// ---------------- embed + input projection for LSTM ----------------
__global__ __launch_bounds__(256) void xproj_k(const int* __restrict__ question,
                                               const float* __restrict__ emb,
                                               const float* __restrict__ wih,
                                               const float* __restrict__ bih,
                                               const float* __restrict__ bhh,
                                               float* __restrict__ xproj) {
  int idx = blockIdx.x * 256 + threadIdx.x;          // 20*64*512
  int gt = idx & 511;
  int b  = (idx >> 9) & 63;
  int t  = idx >> 15;
  int tok = question[b * QLENS + t];
  const float* e  = emb + tok * EMBS;
  const float* wr = wih + gt * EMBS;
  float acc = bih[gt] + bhh[gt];
#pragma unroll
  for (int k = 0; k < EMBS; ++k) acc += wr[k] * e[k];
  xproj[idx] = acc;
}

// ---------------- sequential LSTM, one block per batch element ----------------
__global__ __launch_bounds__(512) void lstm_k(const float* __restrict__ xproj,
                                              const float* __restrict__ whh,
                                              float* __restrict__ qvec) {
  int b = blockIdx.x;
  int gt = threadIdx.x;                               // 0..511
  __shared__ float h[QVSS];
  __shared__ float gates[4 * QVSS];
  float w[QVSS];
#pragma unroll
  for (int k = 0; k < QVSS; ++k) w[k] = whh[gt * QVSS + k];
  float c = 0.0f;
  if (gt < QVSS) h[gt] = 0.0f;
  __syncthreads();
  for (int t = 0; t < QLENS; ++t) {
    float acc = xproj[(t * MBS + b) * 512 + gt];
#pragma unroll
    for (int k = 0; k < QVSS; ++k) acc += w[k] * h[k];
    gates[gt] = acc;
    __syncthreads();
    if (gt < QVSS) {
      float ig = gates[gt];
      float fg = gates[QVSS + gt];
      float gg = gates[2 * QVSS + gt];
      float og = gates[3 * QVSS + gt];
      c = sigm(fg) * c + sigm(ig) * tanhf(gg);
      h[gt] = sigm(og) * tanhf(c);
    }
    __syncthreads();
  }
  if (gt < QVSS) qvec[b * QVSS + gt] = h[gt];
}

// ---------------- direct conv (stride2 pad1 3x3), pure ----------------
template <int CIN, int H>
__global__ __launch_bounds__(256) void conv_k(const float* __restrict__ x,
                                              const float* __restrict__ w,
                                              const float* __restrict__ bias,
                                              float* __restrict__ y) {
  const int OH = H / 2;
  __shared__ float sw[CIN * CHS * 9];
  __shared__ float sb[CHS];
  for (int i = threadIdx.x; i < CIN * CHS * 9; i += 256) sw[i] = w[i];
  if (threadIdx.x < CHS) sb[threadIdx.x] = bias[threadIdx.x];
  __syncthreads();
  int idx = blockIdx.x * 256 + threadIdx.x;           // 64*24*OH*OH, exact grid
  int ow = idx % OH;
  int oh = (idx / OH) % OH;
  int co = (idx / (OH * OH)) % CHS;
  int b  = idx / (CHS * OH * OH);
  float acc = sb[co];
  const float* xb = x + b * CIN * H * H;
#pragma unroll
  for (int kh = 0; kh < 3; ++kh) {
    int ih = oh * 2 - 1 + kh;
    if (ih < 0 || ih >= H) continue;
#pragma unroll
    for (int kw = 0; kw < 3; ++kw) {
      int iw = ow * 2 - 1 + kw;
      if (iw < 0 || iw >= H) continue;
      for (int ci = 0; ci < CIN; ++ci)
        acc += xb[(ci * H + ih) * H + iw] * sw[(co * CIN + ci) * 9 + kh * 3 + kw];
    }
  }
  y[idx] = acc;
}

// ---------------- BN stats: per (channel, sub-range) block, few atomics ----------------
__global__ __launch_bounds__(256) void stats_k(const float* __restrict__ y,
                                               float* __restrict__ st,
                                               int HW, int SUB) {
  int c = blockIdx.x / SUB, sub = blockIdx.x % SUB;
  int bpb = MBS / SUB;
  float s = 0.0f, s2 = 0.0f;
  for (int b = sub * bpb; b < (sub + 1) * bpb; ++b) {
    const float* p = y + (b * CHS + c) * HW;
    for (int i = threadIdx.x * 4; i < HW; i += 1024) {
      float4 v = *reinterpret_cast<const float4*>(p + i);
      s  += v.x + v.y + v.z + v.w;
      s2 += v.x * v.x + v.y * v.y + v.z * v.z + v.w * v.w;
    }
  }
#pragma unroll
  for (int off = 1; off < 64; off <<= 1) {
    s  += __shfl_xor(s, off);
    s2 += __shfl_xor(s2, off);
  }
  __shared__ float rs[4], rs2[4];
  int w = threadIdx.x >> 6;
  if ((threadIdx.x & 63) == 0) { rs[w] = s; rs2[w] = s2; }
  __syncthreads();
  if (threadIdx.x == 0) {
    atomicAdd(&st[c * 2 + 0], rs[0] + rs[1] + rs[2] + rs[3]);
    atomicAdd(&st[c * 2 + 1], rs2[0] + rs2[1] + rs2[2] + rs2[3]);
  }
}

// ---------------- BN apply + relu, in place ----------------
__global__ __launch_bounds__(256) void bn_k(float* __restrict__ y,
                                            const float* __restrict__ st,
                                            const float* __restrict__ g,
                                            const float* __restrict__ beta,
                                            int HW, float inv_cnt) {
  int idx = blockIdx.x * 256 + threadIdx.x;
  int co = (idx / HW) % CHS;
  float m = st[co * 2 + 0] * inv_cnt;
  float v = st[co * 2 + 1] * inv_cnt - m * m;
  float r = rsqrtf(v + 1e-5f);
  float val = (y[idx] - m) * r * g[co] + beta[co];
  y[idx] = fmaxf(val, 0.0f);
}

// ---------------- object projections: pre_i / pre_j ----------------
__global__ __launch_bounds__(256) void preobj_k(const float* __restrict__ x4,
                                                const float* __restrict__ g1w,
                                                float* __restrict__ pre_i,
                                                float* __restrict__ pre_j) {
  int bo = blockIdx.x;                                // 64*64
  int b = bo >> 6, o = bo & 63;
  int n = threadIdx.x;                                // 256
  __shared__ float obj[32];
  if (n < CHS) obj[n] = x4[(b * CHS + n) * NOBJS + o];
  if (n == 24) obj[24] = (float)(o / 8 - 2) * 0.5f;
  if (n == 25) obj[25] = (float)(o % 8 - 2) * 0.5f;
  __syncthreads();
  const float* wr = g1w + n * 180;
  float ai = 0.0f, aj = 0.0f;
#pragma unroll
  for (int f = 0; f < 26; ++f) {
    ai += wr[f] * obj[f];
    aj += wr[26 + f] * obj[f];
  }
  pre_i[bo * GS + n] = ai;
  pre_j[bo * GS + n] = aj;
}

// ---------------- question projection: pre_q (includes g1_b) ----------------
__global__ __launch_bounds__(256) void preq_k(const float* __restrict__ qvec,
                                              const float* __restrict__ g1w,
                                              const float* __restrict__ g1b,
                                              float* __restrict__ pre_q) {
  int b = blockIdx.x;
  int n = threadIdx.x;
  __shared__ float q[QVSS];
  if (n < QVSS) q[n] = qvec[b * QVSS + n];
  __syncthreads();
  const float* wr = g1w + n * 180 + 52;
  float a = g1b[n];
#pragma unroll
  for (int k = 0; k < QVSS; ++k) a += wr[k] * q[k];
  pre_q[b * GS + n] = a;
}

// ---------------- fused relational MLP: 32x32x16 MFMA, single 32KB LDS tile ----------------
// block = (b, j): 64 relation rows x 256 feats; 3 layers fused.
// LDS layout: row-major 64 x 512B rows, byte ^= (row&7)<<4 swizzle.
__global__ __launch_bounds__(256, 4) void rel_k(const float* __restrict__ pre_i,
                                                const float* __restrict__ pre_j,
                                                const float* __restrict__ pre_q,
                                                const unsigned short* __restrict__ wbf,
                                                const float* __restrict__ g2b,
                                                const float* __restrict__ g3b,
                                                const float* __restrict__ g4b,
                                                float* __restrict__ xg) {
  __shared__ short8 hb8[2048];                        // 64 rows x 256 bf16 = 32 KB
  char* hb = (char*)hb8;
  int bid = blockIdx.x;
  int b = bid >> 6, j = bid & 63;
  int tid = threadIdx.x;
  int w = tid >> 6, lane = tid & 63;
  int l31 = lane & 31, lh = lane >> 5;

  // phase 0: h0 = relu(pre_j[b,j] + pre_i[b,i] + pre_q[b])
  {
    int r = tid >> 2, kq = tid & 3;
    const float* pj = pre_j + (b * 64 + j) * GS;
    const float* pi = pre_i + (b * 64 + r) * GS;
    const float* pq = pre_q + b * GS;
    int rowbase = r * 512;
    int sw = (r & 7) << 4;
    for (int kk = 0; kk < 64; kk += 8) {
      int n0 = kq * 64 + kk;
      short8 pack;
#pragma unroll
      for (int e = 0; e < 8; ++e) {
        int n = n0 + e;
        float v = pj[n] + pi[n] + pq[n];
        pack[e] = (short)f2bf(fmaxf(v, 0.0f));
      }
      *(short8*)(hb + rowbase + ((n0 * 2) ^ sw)) = pack;
    }
  }

  const short8* Wv = (const short8*)wbf;
  const int r0 = l31, r1 = 32 + l31;
  const int swA = (l31 & 7) << 4;
  const int aoff = lh * 16;                           // byte offset (k-half) within row
  const int nA = w * 64 + l31;                        // wave's n-tile 0
  const int nB = w * 64 + 32 + l31;                   // wave's n-tile 1

#pragma unroll 1
  for (int L = 0; L < 3; ++L) {
    __syncthreads();                                  // h(L) visible
    const float* bias = (L == 0) ? g2b : ((L == 1) ? g3b : g4b);
    const short8* WL = Wv + L * 8192;
    float biasA = bias[nA], biasB = bias[nB];
    f32x16 acc00 = {}, acc01 = {}, acc10 = {}, acc11 = {};
#pragma unroll 2
    for (int kt = 0; kt < 16; ++kt) {
      int col = kt * 32 + aoff;
      short8 a0 = *(const short8*)(hb + r0 * 512 + (col ^ swA));
      short8 a1 = *(const short8*)(hb + r1 * 512 + (col ^ swA));
      short8 b0 = WL[nA * 32 + kt * 2 + lh];
      short8 b1 = WL[nB * 32 + kt * 2 + lh];
      acc00 = __builtin_amdgcn_mfma_f32_32x32x16_bf16(a0, b0, acc00, 0, 0, 0);
      acc01 = __builtin_amdgcn_mfma_f32_32x32x16_bf16(a0, b1, acc01, 0, 0, 0);
      acc10 = __builtin_amdgcn_mfma_f32_32x32x16_bf16(a1, b0, acc10, 0, 0, 0);
      acc11 = __builtin_amdgcn_mfma_f32_32x32x16_bf16(a1, b1, acc11, 0, 0, 0);
    }
    if (L < 2) {
      __syncthreads();                                // all reads of h(L) done
#pragma unroll
      for (int reg = 0; reg < 16; ++reg) {
        int rr = (reg & 3) + 8 * (reg >> 2) + 4 * lh;
        int rlo = rr, rhi = 32 + rr;
        unsigned short v00 = f2bf(fmaxf(acc00[reg] + biasA, 0.0f));
        unsigned short v01 = f2bf(fmaxf(acc01[reg] + biasB, 0.0f));
        unsigned short v10 = f2bf(fmaxf(acc10[reg] + biasA, 0.0f));
        unsigned short v11 = f2bf(fmaxf(acc11[reg] + biasB, 0.0f));
        int slo = (rlo & 7) << 4, shi = (rhi & 7) << 4;
        *(unsigned short*)(hb + rlo * 512 + ((nA * 2) ^ slo)) = v00;
        *(unsigned short*)(hb + rlo * 512 + ((nB * 2) ^ slo)) = v01;
        *(unsigned short*)(hb + rhi * 512 + ((nA * 2) ^ shi)) = v10;
        *(unsigned short*)(hb + rhi * 512 + ((nB * 2) ^ shi)) = v11;
      }
    } else {
      float sA = 0.0f, sB = 0.0f;
#pragma unroll
      for (int reg = 0; reg < 16; ++reg) {
        sA += fmaxf(acc00[reg] + biasA, 0.0f) + fmaxf(acc10[reg] + biasA, 0.0f);
        sB += fmaxf(acc01[reg] + biasB, 0.0f) + fmaxf(acc11[reg] + biasB, 0.0f);
      }
      sA += __shfl_xor(sA, 32);
      sB += __shfl_xor(sB, 32);
      if (lh == 0) {
        atomicAdd(&xg[b * GS + nA], sA);
        atomicAdd(&xg[b * GS + nB], sB);
      }
    }
  }
}

// ---------------- final f-MLP + log_softmax ----------------
__global__ __launch_bounds__(256) void final_k(const float* __restrict__ xg,
                                               const float* __restrict__ f1w,
                                               const float* __restrict__ f1b,
                                               const float* __restrict__ f2w,
                                               const float* __restrict__ f2b,
                                               const float* __restrict__ f3w,
                                               const float* __restrict__ f3b,
                                               float* __restrict__ out) {
  int b = blockIdx.x, n = threadIdx.x;
  __shared__ float s0[GS], s1[GS], sl[16];
  s0[n] = xg[b * GS + n];
  __syncthreads();
  float a = f1b[n];
  {
    const float4* wr = (const float4*)(f1w + n * GS);
    for (int k = 0; k < GS / 4; ++k) {
      float4 wv = wr[k];
      a += wv.x * s0[k * 4] + wv.y * s0[k * 4 + 1] + wv.z * s0[k * 4 + 2] + wv.w * s0[k * 4 + 3];
    }
  }
  s1[n] = fmaxf(a, 0.0f);
  __syncthreads();
  a = f2b[n];
  {
    const float4* wr = (const float4*)(f2w + n * GS);
    for (int k = 0; k < GS / 4; ++k) {
      float4 wv = wr[k];
      a += wv.x * s1[k * 4] + wv.y * s1[k * 4 + 1] + wv.z * s1[k * 4 + 2] + wv.w * s1[k * 4 + 3];
    }
  }
  s0[n] = fmaxf(a, 0.0f);
  __syncthreads();
  if (n < ANSS) {
    a = f3b[n];
    const float4* wr = (const float4*)(f3w + n * GS);
    for (int k = 0; k < GS / 4; ++k) {
      float4 wv = wr[k];
      a += wv.x * s0[k * 4] + wv.y * s0[k * 4 + 1] + wv.z * s0[k * 4 + 2] + wv.w * s0[k * 4 + 3];
    }
    sl[n] = a;
  }
  __syncthreads();
  if (n == 0) {
    float m = -1e30f;
    for (int i = 0; i < ANSS; ++i) m = fmaxf(m, sl[i]);
    float s = 0.0f;
    for (int i = 0; i < ANSS; ++i) s += expf(sl[i] - m);
    sl[12] = m + logf(s);
  }
  __syncthreads();
  if (n < ANSS) out[b * ANSS + n] = sl[n] - sl[12];
}

extern "C" void kernel_launch(void* const* d_in, const int* in_sizes, int n_in,
                              void* d_out, int out_size, void* d_ws, size_t ws_size,
                              hipStream_t stream) {
  const float* image = (const float*)d_in[0];
  const int*   question = (const int*)d_in[1];
  const float* emb = (const float*)d_in[2];
  const float* wih = (const float*)d_in[3];
  const float* whh = (const float*)d_in[4];
  const float* bih = (const float*)d_in[5];
  const float* bhh = (const float*)d_in[6];
  const float* c1w = (const float*)d_in[7];
  const float* c1b = (const float*)d_in[8];
  const float* bn1g = (const float*)d_in[9];
  const float* bn1b = (const float*)d_in[10];
  const float* c2w = (const float*)d_in[11];
  const float* c2b = (const float*)d_in[12];
  const float* bn2g = (const float*)d_in[13];
  const float* bn2b = (const float*)d_in[14];
  const float* c3w = (const float*)d_in[15];
  const float* c3b = (const float*)d_in[16];
  const float* bn3g = (const float*)d_in[17];
  const float* bn3b = (const float*)d_in[18];
  const float* c4w = (const float*)d_in[19];
  const float* c4b = (const float*)d_in[20];
  const float* bn4g = (const float*)d_in[21];
  const float* bn4b = (const float*)d_in[22];
  const float* g1w = (const float*)d_in[23];
  const float* g1b = (const float*)d_in[24];
  const float* g2w = (const float*)d_in[25];
  const float* g2b = (const float*)d_in[26];
  const float* g3w = (const float*)d_in[27];
  const float* g3b = (const float*)d_in[28];
  const float* g4w = (const float*)d_in[29];
  const float* g4b = (const float*)d_in[30];
  const float* f1w = (const float*)d_in[31];
  const float* f1b = (const float*)d_in[32];
  const float* f2w = (const float*)d_in[33];
  const float* f2b = (const float*)d_in[34];
  const float* f3w = (const float*)d_in[35];
  const float* f3b = (const float*)d_in[36];
  float* out = (float*)d_out;

  float* wsf = (float*)d_ws;
  float* arenaA = wsf;                                // 6,291,456 f
  float* arenaB = wsf + 6291456;                      // 1,572,864 f
  float* xproj  = wsf + 7864320;                      // 655,360 f
  float* qvec   = wsf + 8519680;                      // 8,192 f
  float* pre_i  = wsf + 8527872;                      // 1,048,576 f
  float* pre_j  = wsf + 9576448;                      // 1,048,576 f
  float* pre_q  = wsf + 10625024;                     // 16,384 f
  float* xg     = wsf + 10641408;                     // 16,384 f
  float* stats  = wsf + 10657792;                     // 256 f (4 layers x 24 x 2)
  unsigned short* wbf = (unsigned short*)(wsf + 10658048); // 196,608 bf16

  hipMemsetAsync(xg, 0, (16384 + 256) * sizeof(float), stream);

  wprep_k<<<768, 256, 0, stream>>>(g2w, g3w, g4w, wbf);
  xproj_k<<<2560, 256, 0, stream>>>(question, emb, wih, bih, bhh, xproj);
  lstm_k<<<64, 512, 0, stream>>>(xproj, whh, qvec);

  conv_k<3, 128><<<24576, 256, 0, stream>>>(image, c1w, c1b, arenaA);
  stats_k<<<24 * 16, 256, 0, stream>>>(arenaA, stats + 0, 4096, 16);
  bn_k<<<24576, 256, 0, stream>>>(arenaA, stats + 0, bn1g, bn1b, 4096, 1.0f / 262144.0f);

  conv_k<24, 64><<<6144, 256, 0, stream>>>(arenaA, c2w, c2b, arenaB);
  stats_k<<<24 * 16, 256, 0, stream>>>(arenaB, stats + 48, 1024, 16);
  bn_k<<<6144, 256, 0, stream>>>(arenaB, stats + 48, bn2g, bn2b, 1024, 1.0f / 65536.0f);

  conv_k<24, 32><<<1536, 256, 0, stream>>>(arenaB, c3w, c3b, arenaA);
  stats_k<<<24 * 4, 256, 0, stream>>>(arenaA, stats + 96, 256, 4);
  bn_k<<<1536, 256, 0, stream>>>(arenaA, stats + 96, bn3g, bn3b, 256, 1.0f / 16384.0f);

  conv_k<24, 16><<<384, 256, 0, stream>>>(arenaA, c4w, c4b, arenaB);
  stats_k<<<24, 256, 0, stream>>>(arenaB, stats + 144, 64, 1);
  bn_k<<<384, 256, 0, stream>>>(arenaB, stats + 144, bn4g, bn4b, 64, 1.0f / 4096.0f);

  preobj_k<<<4096, 256, 0, stream>>>(arenaB, g1w, pre_i, pre_j);
  preq_k<<<64, 256, 0, stream>>>(qvec, g1w, g1b, pre_q);

  rel_k<<<4096, 256, 0, stream>>>(pre_i, pre_j, pre_q, wbf, g2b, g3b, g4b, xg);

  final_k<<<64, 256, 0, stream>>>(xg, f1w, f1b, f2w, f2b, f3w, f3b, out);
}

// Round 4
// 747.678 us; speedup vs baseline: 2.7487x; 1.0383x over previous
//
#include <hip/hip_runtime.h>
#include <math.h>

#define MBS   64
#define QLENS 20
#define EMBS  32
#define QVSS  128
#define ANSS  10
#define CHS   24
#define NOBJS 64
#define GS    256

typedef __attribute__((ext_vector_type(8))) short short8;
typedef __attribute__((ext_vector_type(4))) float f32x4;
typedef __attribute__((ext_vector_type(16))) float f32x16;

__device__ __forceinline__ unsigned short f2bf(float f) {
  unsigned u = __float_as_uint(f);
  u += 0x7fffu + ((u >> 16) & 1u);
  return (unsigned short)(u >> 16);
}
__device__ __forceinline__ float sigm(float x) { return 1.0f / (1.0f + expf(-x)); }

// ---------------- weight prep: f32 -> bf16 for g2/g3/g4 ----------------
__global__ __launch_bounds__(256) void wprep_k(const float* __restrict__ g2w,
                                               const float* __restrict__ g3w,
                                               const float* __restrict__ g4w,
                                               unsigned short* __restrict__ wbf) {
  int idx = blockIdx.x * 256 + threadIdx.x;          // 3*65536
  int l = idx >> 16, r = idx & 65535;
  const float* src = (l == 0) ? g2w : ((l == 1) ? g3w : g4w);
  wbf[idx] = f2bf(src[r]);
}

// ---------------- embed + input projection for LSTM ----------------
__global__ __launch_bounds__(256) void xproj_k(const int* __restrict__ question,
                                               const float* __restrict__ emb,
                                               const float* __restrict__ wih,
                                               const float* __restrict__ bih,
                                               const float* __restrict__ bhh,
                                               float* __restrict__ xproj) {
  int idx = blockIdx.x * 256 + threadIdx.x;          // 20*64*512
  int gt = idx & 511;
  int b  = (idx >> 9) & 63;
  int t  = idx >> 15;
  int tok = question[b * QLENS + t];
  const float* e  = emb + tok * EMBS;
  const float* wr = wih + gt * EMBS;
  float acc = bih[gt] + bhh[gt];
#pragma unroll
  for (int k = 0; k < EMBS; ++k) acc += wr[k] * e[k];
  xproj[idx] = acc;
}

// ---------------- sequential LSTM, one block per batch element ----------------
__global__ __launch_bounds__(512) void lstm_k(const float* __restrict__ xproj,
                                              const float* __restrict__ whh,
                                              float* __restrict__ qvec) {
  int b = blockIdx.x;
  int gt = threadIdx.x;                               // 0..511
  __shared__ float h[QVSS];
  __shared__ float gates[4 * QVSS];
  float w[QVSS];
#pragma unroll
  for (int k = 0; k < QVSS; ++k) w[k] = whh[gt * QVSS + k];
  float c = 0.0f;
  if (gt < QVSS) h[gt] = 0.0f;
  __syncthreads();
  for (int t = 0; t < QLENS; ++t) {
    float acc = xproj[(t * MBS + b) * 512 + gt];
#pragma unroll
    for (int k = 0; k < QVSS; ++k) acc += w[k] * h[k];
    gates[gt] = acc;
    __syncthreads();
    if (gt < QVSS) {
      float ig = gates[gt];
      float fg = gates[QVSS + gt];
      float gg = gates[2 * QVSS + gt];
      float og = gates[3 * QVSS + gt];
      c = sigm(fg) * c + sigm(ig) * tanhf(gg);
      h[gt] = sigm(og) * tanhf(c);
    }
    __syncthreads();
  }
  if (gt < QVSS) qvec[b * QVSS + gt] = h[gt];
}

// ---------------- direct conv (stride2 pad1 3x3), pure ----------------
template <int CIN, int H>
__global__ __launch_bounds__(256) void conv_k(const float* __restrict__ x,
                                              const float* __restrict__ w,
                                              const float* __restrict__ bias,
                                              float* __restrict__ y) {
  const int OH = H / 2;
  __shared__ float sw[CIN * CHS * 9];
  __shared__ float sb[CHS];
  for (int i = threadIdx.x; i < CIN * CHS * 9; i += 256) sw[i] = w[i];
  if (threadIdx.x < CHS) sb[threadIdx.x] = bias[threadIdx.x];
  __syncthreads();
  int idx = blockIdx.x * 256 + threadIdx.x;           // 64*24*OH*OH, exact grid
  int ow = idx % OH;
  int oh = (idx / OH) % OH;
  int co = (idx / (OH * OH)) % CHS;
  int b  = idx / (CHS * OH * OH);
  float acc = sb[co];
  const float* xb = x + b * CIN * H * H;
#pragma unroll
  for (int kh = 0; kh < 3; ++kh) {
    int ih = oh * 2 - 1 + kh;
    if (ih < 0 || ih >= H) continue;
#pragma unroll
    for (int kw = 0; kw < 3; ++kw) {
      int iw = ow * 2 - 1 + kw;
      if (iw < 0 || iw >= H) continue;
      for (int ci = 0; ci < CIN; ++ci)
        acc += xb[(ci * H + ih) * H + iw] * sw[(co * CIN + ci) * 9 + kh * 3 + kw];
    }
  }
  y[idx] = acc;
}

// ---------------- BN stats: per (channel, sub-range) block, few atomics ----------------
__global__ __launch_bounds__(256) void stats_k(const float* __restrict__ y,
                                               float* __restrict__ st,
                                               int HW, int SUB) {
  int c = blockIdx.x / SUB, sub = blockIdx.x % SUB;
  int bpb = MBS / SUB;
  float s = 0.0f, s2 = 0.0f;
  for (int b = sub * bpb; b < (sub + 1) * bpb; ++b) {
    const float* p = y + (b * CHS + c) * HW;
    for (int i = threadIdx.x * 4; i < HW; i += 1024) {
      float4 v = *reinterpret_cast<const float4*>(p + i);
      s  += v.x + v.y + v.z + v.w;
      s2 += v.x * v.x + v.y * v.y + v.z * v.z + v.w * v.w;
    }
  }
#pragma unroll
  for (int off = 1; off < 64; off <<= 1) {
    s  += __shfl_xor(s, off);
    s2 += __shfl_xor(s2, off);
  }
  __shared__ float rs[4], rs2[4];
  int w = threadIdx.x >> 6;
  if ((threadIdx.x & 63) == 0) { rs[w] = s; rs2[w] = s2; }
  __syncthreads();
  if (threadIdx.x == 0) {
    atomicAdd(&st[c * 2 + 0], rs[0] + rs[1] + rs[2] + rs[3]);
    atomicAdd(&st[c * 2 + 1], rs2[0] + rs2[1] + rs2[2] + rs2[3]);
  }
}

// ---------------- BN apply + relu, in place ----------------
__global__ __launch_bounds__(256) void bn_k(float* __restrict__ y,
                                            const float* __restrict__ st,
                                            const float* __restrict__ g,
                                            const float* __restrict__ beta,
                                            int HW, float inv_cnt) {
  int idx = blockIdx.x * 256 + threadIdx.x;
  int co = (idx / HW) % CHS;
  float m = st[co * 2 + 0] * inv_cnt;
  float v = st[co * 2 + 1] * inv_cnt - m * m;
  float r = rsqrtf(v + 1e-5f);
  float val = (y[idx] - m) * r * g[co] + beta[co];
  y[idx] = fmaxf(val, 0.0f);
}

// ---------------- object projections: pre_i / pre_j ----------------
__global__ __launch_bounds__(256) void preobj_k(const float* __restrict__ x4,
                                                const float* __restrict__ g1w,
                                                float* __restrict__ pre_i,
                                                float* __restrict__ pre_j) {
  int bo = blockIdx.x;                                // 64*64
  int b = bo >> 6, o = bo & 63;
  int n = threadIdx.x;                                // 256
  __shared__ float obj[32];
  if (n < CHS) obj[n] = x4[(b * CHS + n) * NOBJS + o];
  if (n == 24) obj[24] = (float)(o / 8 - 2) * 0.5f;
  if (n == 25) obj[25] = (float)(o % 8 - 2) * 0.5f;
  __syncthreads();
  const float* wr = g1w + n * 180;
  float ai = 0.0f, aj = 0.0f;
#pragma unroll
  for (int f = 0; f < 26; ++f) {
    ai += wr[f] * obj[f];
    aj += wr[26 + f] * obj[f];
  }
  pre_i[bo * GS + n] = ai;
  pre_j[bo * GS + n] = aj;
}

// ---------------- question projection: pre_q (includes g1_b) ----------------
__global__ __launch_bounds__(256) void preq_k(const float* __restrict__ qvec,
                                              const float* __restrict__ g1w,
                                              const float* __restrict__ g1b,
                                              float* __restrict__ pre_q) {
  int b = blockIdx.x;
  int n = threadIdx.x;
  __shared__ float q[QVSS];
  if (n < QVSS) q[n] = qvec[b * QVSS + n];
  __syncthreads();
  const float* wr = g1w + n * 180 + 52;
  float a = g1b[n];
#pragma unroll
  for (int k = 0; k < QVSS; ++k) a += wr[k] * q[k];
  pre_q[b * GS + n] = a;
}

// ---------------- fused relational MLP: 32x32x16 MFMA, single 32KB LDS tile ----------------
// block = (b, j): 64 relation rows x 256 feats; 3 layers fused.
// LDS: 64 rows x 512 B, swizzle byte ^= (row&31)<<4  -> conflict-free A-reads.
// Output: per-block column partial sums -> xpart[bid][256] (no global atomics).
__global__ __launch_bounds__(256, 4) void rel_k(const float* __restrict__ pre_i,
                                                const float* __restrict__ pre_j,
                                                const float* __restrict__ pre_q,
                                                const unsigned short* __restrict__ wbf,
                                                const float* __restrict__ g2b,
                                                const float* __restrict__ g3b,
                                                const float* __restrict__ g4b,
                                                float* __restrict__ xpart) {
  __shared__ short8 hb8[2048];                        // 64 rows x 256 bf16 = 32 KB
  char* hb = (char*)hb8;
  int bid = blockIdx.x;
  int b = bid >> 6, j = bid & 63;
  int tid = threadIdx.x;
  int w = tid >> 6, lane = tid & 63;
  int l31 = lane & 31, lh = lane >> 5;

  // phase 0: h0 = relu(pre_j[b,j] + pre_i[b,i] + pre_q[b]); row = lane, col quarter = wave
  {
    int r = tid & 63, kc = tid >> 6;
    const float* pj = pre_j + (b * 64 + j) * GS;
    const float* pi = pre_i + (b * 64 + r) * GS;
    const float* pq = pre_q + b * GS;
    int rowbase = r * 512;
    int sw = (r & 31) << 4;
#pragma unroll
    for (int kk = 0; kk < 8; ++kk) {
      int n0 = kc * 64 + kk * 8;
      float4 va  = *(const float4*)(pi + n0);
      float4 va2 = *(const float4*)(pi + n0 + 4);
      float4 vj  = *(const float4*)(pj + n0);
      float4 vj2 = *(const float4*)(pj + n0 + 4);
      float4 vq  = *(const float4*)(pq + n0);
      float4 vq2 = *(const float4*)(pq + n0 + 4);
      short8 pack;
      pack[0] = (short)f2bf(fmaxf(va.x  + vj.x  + vq.x,  0.0f));
      pack[1] = (short)f2bf(fmaxf(va.y  + vj.y  + vq.y,  0.0f));
      pack[2] = (short)f2bf(fmaxf(va.z  + vj.z  + vq.z,  0.0f));
      pack[3] = (short)f2bf(fmaxf(va.w  + vj.w  + vq.w,  0.0f));
      pack[4] = (short)f2bf(fmaxf(va2.x + vj2.x + vq2.x, 0.0f));
      pack[5] = (short)f2bf(fmaxf(va2.y + vj2.y + vq2.y, 0.0f));
      pack[6] = (short)f2bf(fmaxf(va2.z + vj2.z + vq2.z, 0.0f));
      pack[7] = (short)f2bf(fmaxf(va2.w + vj2.w + vq2.w, 0.0f));
      *(short8*)(hb + rowbase + ((n0 * 2) ^ sw)) = pack;
    }
  }

  const short8* Wv = (const short8*)wbf;
  const int r0 = l31, r1 = 32 + l31;
  const int swA = l31 << 4;                           // (row&31)<<4, same for r0/r1
  const int aoff = lh * 16;                           // byte offset (k-half) within row
  const int nA = w * 64 + l31;                        // wave's n-tile 0
  const int nB = w * 64 + 32 + l31;                   // wave's n-tile 1

#pragma unroll 1
  for (int L = 0; L < 3; ++L) {
    __syncthreads();                                  // h(L) visible
    const float* bias = (L == 0) ? g2b : ((L == 1) ? g3b : g4b);
    const short8* WL = Wv + L * 8192;
    float biasA = bias[nA], biasB = bias[nB];
    f32x16 acc00 = {}, acc01 = {}, acc10 = {}, acc11 = {};
#pragma unroll 2
    for (int kt = 0; kt < 16; ++kt) {
      int col = kt * 32 + aoff;
      short8 a0 = *(const short8*)(hb + r0 * 512 + (col ^ swA));
      short8 a1 = *(const short8*)(hb + r1 * 512 + (col ^ swA));
      short8 b0 = WL[nA * 32 + kt * 2 + lh];
      short8 b1 = WL[nB * 32 + kt * 2 + lh];
      acc00 = __builtin_amdgcn_mfma_f32_32x32x16_bf16(a0, b0, acc00, 0, 0, 0);
      acc01 = __builtin_amdgcn_mfma_f32_32x32x16_bf16(a0, b1, acc01, 0, 0, 0);
      acc10 = __builtin_amdgcn_mfma_f32_32x32x16_bf16(a1, b0, acc10, 0, 0, 0);
      acc11 = __builtin_amdgcn_mfma_f32_32x32x16_bf16(a1, b1, acc11, 0, 0, 0);
    }
    if (L < 2) {
      __syncthreads();                                // all reads of h(L) done
#pragma unroll
      for (int reg = 0; reg < 16; ++reg) {
        int rr = (reg & 3) + 8 * (reg >> 2) + 4 * lh; // 0..31
        int swr = rr << 4;                            // (row&31)<<4, same for rr / rr+32
        unsigned short v00 = f2bf(fmaxf(acc00[reg] + biasA, 0.0f));
        unsigned short v01 = f2bf(fmaxf(acc01[reg] + biasB, 0.0f));
        unsigned short v10 = f2bf(fmaxf(acc10[reg] + biasA, 0.0f));
        unsigned short v11 = f2bf(fmaxf(acc11[reg] + biasB, 0.0f));
        *(unsigned short*)(hb + rr * 512        + ((nA * 2) ^ swr)) = v00;
        *(unsigned short*)(hb + rr * 512        + ((nB * 2) ^ swr)) = v01;
        *(unsigned short*)(hb + (32 + rr) * 512 + ((nA * 2) ^ swr)) = v10;
        *(unsigned short*)(hb + (32 + rr) * 512 + ((nB * 2) ^ swr)) = v11;
      }
    } else {
      // column sums over all 64 rows -> LDS -> one coalesced 1KB write per block
      float sA = 0.0f, sB = 0.0f;
#pragma unroll
      for (int reg = 0; reg < 16; ++reg) {
        sA += fmaxf(acc00[reg] + biasA, 0.0f) + fmaxf(acc10[reg] + biasA, 0.0f);
        sB += fmaxf(acc01[reg] + biasB, 0.0f) + fmaxf(acc11[reg] + biasB, 0.0f);
      }
      sA += __shfl_xor(sA, 32);
      sB += __shfl_xor(sB, 32);
      __syncthreads();                                // all K-loop LDS reads done
      float* fs = (float*)hb;
      if (lh == 0) {
        fs[nA] = sA;
        fs[nB] = sB;
      }
      __syncthreads();
      xpart[bid * GS + tid] = fs[tid];
    }
  }
}

// ---------------- final: reduce xpart over j + f-MLP + log_softmax ----------------
__global__ __launch_bounds__(256) void final_k(const float* __restrict__ xpart,
                                               const float* __restrict__ f1w,
                                               const float* __restrict__ f1b,
                                               const float* __restrict__ f2w,
                                               const float* __restrict__ f2b,
                                               const float* __restrict__ f3w,
                                               const float* __restrict__ f3b,
                                               float* __restrict__ out) {
  int b = blockIdx.x, n = threadIdx.x;
  __shared__ float s0[GS], s1[GS], sl[16];
  float xs = 0.0f;
  for (int j = 0; j < 64; ++j) xs += xpart[(b * 64 + j) * GS + n];
  s0[n] = xs;
  __syncthreads();
  float a = f1b[n];
  {
    const float4* wr = (const float4*)(f1w + n * GS);
    for (int k = 0; k < GS / 4; ++k) {
      float4 wv = wr[k];
      a += wv.x * s0[k * 4] + wv.y * s0[k * 4 + 1] + wv.z * s0[k * 4 + 2] + wv.w * s0[k * 4 + 3];
    }
  }
  s1[n] = fmaxf(a, 0.0f);
  __syncthreads();
  a = f2b[n];
  {
    const float4* wr = (const float4*)(f2w + n * GS);
    for (int k = 0; k < GS / 4; ++k) {
      float4 wv = wr[k];
      a += wv.x * s1[k * 4] + wv.y * s1[k * 4 + 1] + wv.z * s1[k * 4 + 2] + wv.w * s1[k * 4 + 3];
    }
  }
  s0[n] = fmaxf(a, 0.0f);
  __syncthreads();
  if (n < ANSS) {
    a = f3b[n];
    const float4* wr = (const float4*)(f3w + n * GS);
    for (int k = 0; k < GS / 4; ++k) {
      float4 wv = wr[k];
      a += wv.x * s0[k * 4] + wv.y * s0[k * 4 + 1] + wv.z * s0[k * 4 + 2] + wv.w * s0[k * 4 + 3];
    }
    sl[n] = a;
  }
  __syncthreads();
  if (n == 0) {
    float m = -1e30f;
    for (int i = 0; i < ANSS; ++i) m = fmaxf(m, sl[i]);
    float s = 0.0f;
    for (int i = 0; i < ANSS; ++i) s += expf(sl[i] - m);
    sl[12] = m + logf(s);
  }
  __syncthreads();
  if (n < ANSS) out[b * ANSS + n] = sl[n] - sl[12];
}

extern "C" void kernel_launch(void* const* d_in, const int* in_sizes, int n_in,
                              void* d_out, int out_size, void* d_ws, size_t ws_size,
                              hipStream_t stream) {
  const float* image = (const float*)d_in[0];
  const int*   question = (const int*)d_in[1];
  const float* emb = (const float*)d_in[2];
  const float* wih = (const float*)d_in[3];
  const float* whh = (const float*)d_in[4];
  const float* bih = (const float*)d_in[5];
  const float* bhh = (const float*)d_in[6];
  const float* c1w = (const float*)d_in[7];
  const float* c1b = (const float*)d_in[8];
  const float* bn1g = (const float*)d_in[9];
  const float* bn1b = (const float*)d_in[10];
  const float* c2w = (const float*)d_in[11];
  const float* c2b = (const float*)d_in[12];
  const float* bn2g = (const float*)d_in[13];
  const float* bn2b = (const float*)d_in[14];
  const float* c3w = (const float*)d_in[15];
  const float* c3b = (const float*)d_in[16];
  const float* bn3g = (const float*)d_in[17];
  const float* bn3b = (const float*)d_in[18];
  const float* c4w = (const float*)d_in[19];
  const float* c4b = (const float*)d_in[20];
  const float* bn4g = (const float*)d_in[21];
  const float* bn4b = (const float*)d_in[22];
  const float* g1w = (const float*)d_in[23];
  const float* g1b = (const float*)d_in[24];
  const float* g2w = (const float*)d_in[25];
  const float* g2b = (const float*)d_in[26];
  const float* g3w = (const float*)d_in[27];
  const float* g3b = (const float*)d_in[28];
  const float* g4w = (const float*)d_in[29];
  const float* g4b = (const float*)d_in[30];
  const float* f1w = (const float*)d_in[31];
  const float* f1b = (const float*)d_in[32];
  const float* f2w = (const float*)d_in[33];
  const float* f2b = (const float*)d_in[34];
  const float* f3w = (const float*)d_in[35];
  const float* f3b = (const float*)d_in[36];
  float* out = (float*)d_out;

  float* wsf = (float*)d_ws;
  float* arenaA = wsf;                                // 6,291,456 f (convs; later xpart 1,048,576 f)
  float* arenaB = wsf + 6291456;                      // 1,572,864 f
  float* xproj  = wsf + 7864320;                      // 655,360 f
  float* qvec   = wsf + 8519680;                      // 8,192 f
  float* pre_i  = wsf + 8527872;                      // 1,048,576 f
  float* pre_j  = wsf + 9576448;                      // 1,048,576 f
  float* pre_q  = wsf + 10625024;                     // 16,384 f
  float* stats  = wsf + 10657792;                     // 256 f (4 layers x 24 x 2)
  unsigned short* wbf = (unsigned short*)(wsf + 10658048); // 196,608 bf16
  float* xpart  = arenaA;                             // reuse: convs done before rel_k

  hipMemsetAsync(stats, 0, 256 * sizeof(float), stream);

  wprep_k<<<768, 256, 0, stream>>>(g2w, g3w, g4w, wbf);
  xproj_k<<<2560, 256, 0, stream>>>(question, emb, wih, bih, bhh, xproj);
  lstm_k<<<64, 512, 0, stream>>>(xproj, whh, qvec);

  conv_k<3, 128><<<24576, 256, 0, stream>>>(image, c1w, c1b, arenaA);
  stats_k<<<24 * 16, 256, 0, stream>>>(arenaA, stats + 0, 4096, 16);
  bn_k<<<24576, 256, 0, stream>>>(arenaA, stats + 0, bn1g, bn1b, 4096, 1.0f / 262144.0f);

  conv_k<24, 64><<<6144, 256, 0, stream>>>(arenaA, c2w, c2b, arenaB);
  stats_k<<<24 * 16, 256, 0, stream>>>(arenaB, stats + 48, 1024, 16);
  bn_k<<<6144, 256, 0, stream>>>(arenaB, stats + 48, bn2g, bn2b, 1024, 1.0f / 65536.0f);

  conv_k<24, 32><<<1536, 256, 0, stream>>>(arenaB, c3w, c3b, arenaA);
  stats_k<<<24 * 4, 256, 0, stream>>>(arenaA, stats + 96, 256, 4);
  bn_k<<<1536, 256, 0, stream>>>(arenaA, stats + 96, bn3g, bn3b, 256, 1.0f / 16384.0f);

  conv_k<24, 16><<<384, 256, 0, stream>>>(arenaA, c4w, c4b, arenaB);
  stats_k<<<24, 256, 0, stream>>>(arenaB, stats + 144, 64, 1);
  bn_k<<<384, 256, 0, stream>>>(arenaB, stats + 144, bn4g, bn4b, 64, 1.0f / 4096.0f);

  preobj_k<<<4096, 256, 0, stream>>>(arenaB, g1w, pre_i, pre_j);
  preq_k<<<64, 256, 0, stream>>>(qvec, g1w, g1b, pre_q);

  rel_k<<<4096, 256, 0, stream>>>(pre_i, pre_j, pre_q, wbf, g2b, g3b, g4b, xpart);

  final_k<<<64, 256, 0, stream>>>(xpart, f1w, f1b, f2w, f2b, f3w, f3b, out);
}

// Round 5
// 617.867 us; speedup vs baseline: 3.3261x; 1.2101x over previous
//
#include <hip/hip_runtime.h>
#include <math.h>

#define MBS   64
#define QLENS 20
#define EMBS  32
#define QVSS  128
#define ANSS  10
#define CHS   24
#define NOBJS 64
#define GS    256

typedef __attribute__((ext_vector_type(8))) short short8;
typedef __attribute__((ext_vector_type(4))) float f32x4;
typedef __attribute__((ext_vector_type(16))) float f32x16;

__device__ __forceinline__ unsigned short f2bf(float f) {
  unsigned u = __float_as_uint(f);
  u += 0x7fffu + ((u >> 16) & 1u);
  return (unsigned short)(u >> 16);
}
__device__ __forceinline__ float sigm(float x) { return 1.0f / (1.0f + expf(-x)); }

// ---------------- weight prep: f32 -> bf16, k-chunk-major [48][256][16] ----------------
// chunk c = L*16+kt holds all 256 n rows of k-slice [kt*16, kt*16+16)
__global__ __launch_bounds__(256) void wprep_k(const float* __restrict__ g2w,
                                               const float* __restrict__ g3w,
                                               const float* __restrict__ g4w,
                                               unsigned short* __restrict__ wbf) {
  int idx = blockIdx.x * 256 + threadIdx.x;          // dst index, 3*65536
  int l = idx >> 16, r = idx & 65535;
  int kt = r >> 12, rem = r & 4095;
  int n = rem >> 4, kk = rem & 15;
  const float* src = (l == 0) ? g2w : ((l == 1) ? g3w : g4w);
  wbf[idx] = f2bf(src[n * 256 + kt * 16 + kk]);
}

// ---------------- fused embed+proj + sequential LSTM, one block per batch ----------------
__global__ __launch_bounds__(512) void lstm_k(const int* __restrict__ question,
                                              const float* __restrict__ emb,
                                              const float* __restrict__ wih,
                                              const float* __restrict__ bih,
                                              const float* __restrict__ bhh,
                                              const float* __restrict__ whh,
                                              float* __restrict__ qvec) {
  int b = blockIdx.x;
  int gt = threadIdx.x;                               // 0..511
  __shared__ float h[QVSS];
  __shared__ float gates[4 * QVSS];
  __shared__ int toks[QLENS];
  float w[QVSS];
#pragma unroll
  for (int k = 0; k < QVSS; ++k) w[k] = whh[gt * QVSS + k];
  float wi[EMBS];
#pragma unroll
  for (int k = 0; k < EMBS; ++k) wi[k] = wih[gt * EMBS + k];
  float bb = bih[gt] + bhh[gt];
  if (gt < QLENS) toks[gt] = question[b * QLENS + gt];
  float c = 0.0f;
  if (gt < QVSS) h[gt] = 0.0f;
  __syncthreads();
  float xp[QLENS];
#pragma unroll
  for (int t = 0; t < QLENS; ++t) {
    const float* e = emb + toks[t] * EMBS;
    float a = bb;
#pragma unroll
    for (int k = 0; k < EMBS; ++k) a += wi[k] * e[k];
    xp[t] = a;
  }
  for (int t = 0; t < QLENS; ++t) {
    float acc = xp[t];
#pragma unroll
    for (int k = 0; k < QVSS; ++k) acc += w[k] * h[k];
    gates[gt] = acc;
    __syncthreads();
    if (gt < QVSS) {
      float ig = gates[gt];
      float fg = gates[QVSS + gt];
      float gg = gates[2 * QVSS + gt];
      float og = gates[3 * QVSS + gt];
      c = sigm(fg) * c + sigm(ig) * tanhf(gg);
      h[gt] = sigm(og) * tanhf(c);
    }
    __syncthreads();
  }
  if (gt < QVSS) qvec[b * QVSS + gt] = h[gt];
}

// ---------------- direct conv (stride2 pad1 3x3), pure ----------------
template <int CIN, int H>
__global__ __launch_bounds__(256) void conv_k(const float* __restrict__ x,
                                              const float* __restrict__ w,
                                              const float* __restrict__ bias,
                                              float* __restrict__ y) {
  const int OH = H / 2;
  __shared__ float sw[CIN * CHS * 9];
  __shared__ float sb[CHS];
  for (int i = threadIdx.x; i < CIN * CHS * 9; i += 256) sw[i] = w[i];
  if (threadIdx.x < CHS) sb[threadIdx.x] = bias[threadIdx.x];
  __syncthreads();
  int idx = blockIdx.x * 256 + threadIdx.x;           // 64*24*OH*OH, exact grid
  int ow = idx % OH;
  int oh = (idx / OH) % OH;
  int co = (idx / (OH * OH)) % CHS;
  int b  = idx / (CHS * OH * OH);
  float acc = sb[co];
  const float* xb = x + b * CIN * H * H;
#pragma unroll
  for (int kh = 0; kh < 3; ++kh) {
    int ih = oh * 2 - 1 + kh;
    if (ih < 0 || ih >= H) continue;
#pragma unroll
    for (int kw = 0; kw < 3; ++kw) {
      int iw = ow * 2 - 1 + kw;
      if (iw < 0 || iw >= H) continue;
      for (int ci = 0; ci < CIN; ++ci)
        acc += xb[(ci * H + ih) * H + iw] * sw[(co * CIN + ci) * 9 + kh * 3 + kw];
    }
  }
  y[idx] = acc;
}

// ---------------- BN stats: per (channel, sub-range) block, few atomics ----------------
__global__ __launch_bounds__(256) void stats_k(const float* __restrict__ y,
                                               float* __restrict__ st,
                                               int HW, int SUB) {
  int c = blockIdx.x / SUB, sub = blockIdx.x % SUB;
  int bpb = MBS / SUB;
  float s = 0.0f, s2 = 0.0f;
  for (int b = sub * bpb; b < (sub + 1) * bpb; ++b) {
    const float* p = y + (b * CHS + c) * HW;
    for (int i = threadIdx.x * 4; i < HW; i += 1024) {
      float4 v = *reinterpret_cast<const float4*>(p + i);
      s  += v.x + v.y + v.z + v.w;
      s2 += v.x * v.x + v.y * v.y + v.z * v.z + v.w * v.w;
    }
  }
#pragma unroll
  for (int off = 1; off < 64; off <<= 1) {
    s  += __shfl_xor(s, off);
    s2 += __shfl_xor(s2, off);
  }
  __shared__ float rs[4], rs2[4];
  int w = threadIdx.x >> 6;
  if ((threadIdx.x & 63) == 0) { rs[w] = s; rs2[w] = s2; }
  __syncthreads();
  if (threadIdx.x == 0) {
    atomicAdd(&st[c * 2 + 0], rs[0] + rs[1] + rs[2] + rs[3]);
    atomicAdd(&st[c * 2 + 1], rs2[0] + rs2[1] + rs2[2] + rs2[3]);
  }
}

// ---------------- BN apply + relu, in place ----------------
__global__ __launch_bounds__(256) void bn_k(float* __restrict__ y,
                                            const float* __restrict__ st,
                                            const float* __restrict__ g,
                                            const float* __restrict__ beta,
                                            int HW, float inv_cnt) {
  int idx = blockIdx.x * 256 + threadIdx.x;
  int co = (idx / HW) % CHS;
  float m = st[co * 2 + 0] * inv_cnt;
  float v = st[co * 2 + 1] * inv_cnt - m * m;
  float r = rsqrtf(v + 1e-5f);
  float val = (y[idx] - m) * r * g[co] + beta[co];
  y[idx] = fmaxf(val, 0.0f);
}

// ---------------- fused bn4 + object projections + question projection ----------------
__global__ __launch_bounds__(256) void pre_k(const float* __restrict__ x4raw,
                                             const float* __restrict__ st,
                                             const float* __restrict__ g,
                                             const float* __restrict__ beta,
                                             const float* __restrict__ g1w,
                                             const float* __restrict__ g1b,
                                             const float* __restrict__ qvec,
                                             float* __restrict__ pre_i,
                                             float* __restrict__ pre_j,
                                             float* __restrict__ pre_q) {
  int bo = blockIdx.x;                                // 4096 obj blocks + 64 q blocks
  int n = threadIdx.x;                                // 256
  __shared__ float sm[QVSS];
  if (bo < 4096) {
    int b = bo >> 6, o = bo & 63;
    if (n < CHS) {
      float m = st[n * 2 + 0] * (1.0f / 4096.0f);
      float v = st[n * 2 + 1] * (1.0f / 4096.0f) - m * m;
      float xv = x4raw[(b * CHS + n) * NOBJS + o];
      sm[n] = fmaxf((xv - m) * rsqrtf(v + 1e-5f) * g[n] + beta[n], 0.0f);
    }
    if (n == 24) sm[24] = (float)(o / 8 - 2) * 0.5f;
    if (n == 25) sm[25] = (float)(o % 8 - 2) * 0.5f;
    __syncthreads();
    const float* wr = g1w + n * 180;
    float ai = 0.0f, aj = 0.0f;
#pragma unroll
    for (int f = 0; f < 26; ++f) {
      ai += wr[f] * sm[f];
      aj += wr[26 + f] * sm[f];
    }
    pre_i[bo * GS + n] = ai;
    pre_j[bo * GS + n] = aj;
  } else {
    int b = bo - 4096;
    if (n < QVSS) sm[n] = qvec[b * QVSS + n];
    __syncthreads();
    const float* wr = g1w + n * 180 + 52;
    float a = g1b[n];
#pragma unroll
    for (int k = 0; k < QVSS; ++k) a += wr[k] * sm[k];
    pre_q[b * GS + n] = a;
  }
}

// ---------------- fused relational MLP: 32x32x16 MFMA, LDS-staged weights ----------------
// block = (b, j): 64 rows x 256 feats; 3 layers fused.
// h: 64 rows x 512 B, byte ^= (row&31)<<4 (conflict-free, verified round 4).
// B: double-buffered 8 KB chunks [256 n][32 B], reg-staged 1 chunk ahead of consumption;
//    raw s_barrier + lgkmcnt(0) so the in-flight global loads are never drained.
__global__ __launch_bounds__(256, 3) void rel_k(const float* __restrict__ pre_i,
                                                const float* __restrict__ pre_j,
                                                const float* __restrict__ pre_q,
                                                const unsigned short* __restrict__ wbf,
                                                const float* __restrict__ g2b,
                                                const float* __restrict__ g3b,
                                                const float* __restrict__ g4b,
                                                float* __restrict__ xpart) {
  __shared__ short8 hb8[2048];                        // 32 KB h tile
  __shared__ short8 wb8[2][512];                      // 2 x 8 KB B chunks
  char* hb  = (char*)hb8;
  char* wbl = (char*)&wb8[0][0];
  char* wbh = (char*)&wb8[1][0];
  int bid = blockIdx.x;
  int b = bid >> 6, j = bid & 63;
  int tid = threadIdx.x;
  int w = tid >> 6, lane = tid & 63;
  int l31 = lane & 31, lh = lane >> 5;

  const short8* Wt = (const short8*)wbf;              // 48 chunks x 512 short8
  const int pidx = w * 64 + lane;                     // piece index (short8) in chunk half
  // prefetch chunk 0 into regs
  short8 rva = Wt[pidx];
  short8 rvb = Wt[256 + pidx];

  // phase 0: h0 = relu(pre_j[b,j] + pre_i[b,i] + pre_q[b]); row = lane, col quarter = wave
  {
    int r = tid & 63, kc = tid >> 6;
    const float* pj = pre_j + (b * 64 + j) * GS;
    const float* pi = pre_i + (b * 64 + r) * GS;
    const float* pq = pre_q + b * GS;
    int rowbase = r * 512;
    int sw = (r & 31) << 4;
#pragma unroll
    for (int kk = 0; kk < 8; ++kk) {
      int n0 = kc * 64 + kk * 8;
      float4 va  = *(const float4*)(pi + n0);
      float4 va2 = *(const float4*)(pi + n0 + 4);
      float4 vj  = *(const float4*)(pj + n0);
      float4 vj2 = *(const float4*)(pj + n0 + 4);
      float4 vq  = *(const float4*)(pq + n0);
      float4 vq2 = *(const float4*)(pq + n0 + 4);
      short8 pack;
      pack[0] = (short)f2bf(fmaxf(va.x  + vj.x  + vq.x,  0.0f));
      pack[1] = (short)f2bf(fmaxf(va.y  + vj.y  + vq.y,  0.0f));
      pack[2] = (short)f2bf(fmaxf(va.z  + vj.z  + vq.z,  0.0f));
      pack[3] = (short)f2bf(fmaxf(va.w  + vj.w  + vq.w,  0.0f));
      pack[4] = (short)f2bf(fmaxf(va2.x + vj2.x + vq2.x, 0.0f));
      pack[5] = (short)f2bf(fmaxf(va2.y + vj2.y + vq2.y, 0.0f));
      pack[6] = (short)f2bf(fmaxf(va2.z + vj2.z + vq2.z, 0.0f));
      pack[7] = (short)f2bf(fmaxf(va2.w + vj2.w + vq2.w, 0.0f));
      *(short8*)(hb + rowbase + ((n0 * 2) ^ sw)) = pack;
    }
  }

  // stage chunk 0, prefetch chunk 1
  *(short8*)(wbl + pidx * 16) = rva;
  *(short8*)(wbl + 4096 + pidx * 16) = rvb;
  rva = Wt[512 + pidx];
  rvb = Wt[512 + 256 + pidx];
  asm volatile("s_waitcnt lgkmcnt(0)" ::: "memory");
  __builtin_amdgcn_s_barrier();
  __builtin_amdgcn_sched_barrier(0);

  const int rA0 = l31 * 512;
  const int rA1 = (32 + l31) * 512;
  const int swA = l31 << 4;
  const int nA = w * 64 + l31, nB = nA + 32;
  const int bOffA = nA * 32 + lh * 16;                // byte offset in chunk
  const int bOffB = bOffA + 1024;                     // +32 n rows

#pragma unroll 1
  for (int L = 0; L < 3; ++L) {
    const float* bias = (L == 0) ? g2b : ((L == 1) ? g3b : g4b);
    float biasA = bias[nA], biasB = bias[nB];
    f32x16 acc00 = {}, acc01 = {}, acc10 = {}, acc11 = {};
#pragma unroll 1
    for (int kt = 0; kt < 16; ++kt) {
      int c = L * 16 + kt;
      char* rbuf = (c & 1) ? wbh : wbl;
      char* sbuf = (c & 1) ? wbl : wbh;
      int colb = (kt * 32 + lh * 16) ^ swA;
      short8 a0 = *(const short8*)(hb + rA0 + colb);
      short8 a1 = *(const short8*)(hb + rA1 + colb);
      short8 b0 = *(const short8*)(rbuf + bOffA);
      short8 b1 = *(const short8*)(rbuf + bOffB);
      acc00 = __builtin_amdgcn_mfma_f32_32x32x16_bf16(a0, b0, acc00, 0, 0, 0);
      acc01 = __builtin_amdgcn_mfma_f32_32x32x16_bf16(a0, b1, acc01, 0, 0, 0);
      acc10 = __builtin_amdgcn_mfma_f32_32x32x16_bf16(a1, b0, acc10, 0, 0, 0);
      acc11 = __builtin_amdgcn_mfma_f32_32x32x16_bf16(a1, b1, acc11, 0, 0, 0);
      if (c < 47) {                                   // stage chunk c+1 (in regs) to LDS
        *(short8*)(sbuf + pidx * 16) = rva;
        *(short8*)(sbuf + 4096 + pidx * 16) = rvb;
        if (c < 46) {                                 // prefetch chunk c+2 to regs
          rva = Wt[(c + 2) * 512 + pidx];
          rvb = Wt[(c + 2) * 512 + 256 + pidx];
        }
      }
      asm volatile("s_waitcnt lgkmcnt(0)" ::: "memory");
      __builtin_amdgcn_s_barrier();                   // publish chunk c+1; h reads of this kt done
      __builtin_amdgcn_sched_barrier(0);
    }
    if (L < 2) {
      // epilogue: bias + relu -> bf16 -> hb (all h(L) reads completed at last barrier)
#pragma unroll
      for (int reg = 0; reg < 16; ++reg) {
        int rr = (reg & 3) + 8 * (reg >> 2) + 4 * lh; // 0..31
        int swr = rr << 4;
        unsigned short v00 = f2bf(fmaxf(acc00[reg] + biasA, 0.0f));
        unsigned short v01 = f2bf(fmaxf(acc01[reg] + biasB, 0.0f));
        unsigned short v10 = f2bf(fmaxf(acc10[reg] + biasA, 0.0f));
        unsigned short v11 = f2bf(fmaxf(acc11[reg] + biasB, 0.0f));
        *(unsigned short*)(hb + rr * 512        + ((nA * 2) ^ swr)) = v00;
        *(unsigned short*)(hb + rr * 512        + ((nB * 2) ^ swr)) = v01;
        *(unsigned short*)(hb + (32 + rr) * 512 + ((nA * 2) ^ swr)) = v10;
        *(unsigned short*)(hb + (32 + rr) * 512 + ((nB * 2) ^ swr)) = v11;
      }
      asm volatile("s_waitcnt lgkmcnt(0)" ::: "memory");
      __builtin_amdgcn_s_barrier();                   // h(L+1) visible
      __builtin_amdgcn_sched_barrier(0);
    } else {
      // column sums over 64 rows -> LDS -> one coalesced 1KB write per block
      float sA = 0.0f, sB = 0.0f;
#pragma unroll
      for (int reg = 0; reg < 16; ++reg) {
        sA += fmaxf(acc00[reg] + biasA, 0.0f) + fmaxf(acc10[reg] + biasA, 0.0f);
        sB += fmaxf(acc01[reg] + biasB, 0.0f) + fmaxf(acc11[reg] + biasB, 0.0f);
      }
      sA += __shfl_xor(sA, 32);
      sB += __shfl_xor(sB, 32);
      float* fs = (float*)wbl;
      if (lh == 0) {
        fs[nA] = sA;
        fs[nB] = sB;
      }
      asm volatile("s_waitcnt lgkmcnt(0)" ::: "memory");
      __builtin_amdgcn_s_barrier();
      __builtin_amdgcn_sched_barrier(0);
      xpart[bid * GS + tid] = fs[tid];
    }
  }
}

// ---------------- final: reduce xpart over j + f-MLP + log_softmax ----------------
__global__ __launch_bounds__(256) void final_k(const float* __restrict__ xpart,
                                               const float* __restrict__ f1w,
                                               const float* __restrict__ f1b,
                                               const float* __restrict__ f2w,
                                               const float* __restrict__ f2b,
                                               const float* __restrict__ f3w,
                                               const float* __restrict__ f3b,
                                               float* __restrict__ out) {
  int b = blockIdx.x, n = threadIdx.x;
  __shared__ float s0[GS], s1[GS], sl[16];
  float xs = 0.0f;
  for (int j = 0; j < 64; ++j) xs += xpart[(b * 64 + j) * GS + n];
  s0[n] = xs;
  __syncthreads();
  float a = f1b[n];
  {
    const float4* wr = (const float4*)(f1w + n * GS);
    for (int k = 0; k < GS / 4; ++k) {
      float4 wv = wr[k];
      a += wv.x * s0[k * 4] + wv.y * s0[k * 4 + 1] + wv.z * s0[k * 4 + 2] + wv.w * s0[k * 4 + 3];
    }
  }
  s1[n] = fmaxf(a, 0.0f);
  __syncthreads();
  a = f2b[n];
  {
    const float4* wr = (const float4*)(f2w + n * GS);
    for (int k = 0; k < GS / 4; ++k) {
      float4 wv = wr[k];
      a += wv.x * s1[k * 4] + wv.y * s1[k * 4 + 1] + wv.z * s1[k * 4 + 2] + wv.w * s1[k * 4 + 3];
    }
  }
  s0[n] = fmaxf(a, 0.0f);
  __syncthreads();
  if (n < ANSS) {
    a = f3b[n];
    const float4* wr = (const float4*)(f3w + n * GS);
    for (int k = 0; k < GS / 4; ++k) {
      float4 wv = wr[k];
      a += wv.x * s0[k * 4] + wv.y * s0[k * 4 + 1] + wv.z * s0[k * 4 + 2] + wv.w * s0[k * 4 + 3];
    }
    sl[n] = a;
  }
  __syncthreads();
  if (n == 0) {
    float m = -1e30f;
    for (int i = 0; i < ANSS; ++i) m = fmaxf(m, sl[i]);
    float s = 0.0f;
    for (int i = 0; i < ANSS; ++i) s += expf(sl[i] - m);
    sl[12] = m + logf(s);
  }
  __syncthreads();
  if (n < ANSS) out[b * ANSS + n] = sl[n] - sl[12];
}

extern "C" void kernel_launch(void* const* d_in, const int* in_sizes, int n_in,
                              void* d_out, int out_size, void* d_ws, size_t ws_size,
                              hipStream_t stream) {
  const float* image = (const float*)d_in[0];
  const int*   question = (const int*)d_in[1];
  const float* emb = (const float*)d_in[2];
  const float* wih = (const float*)d_in[3];
  const float* whh = (const float*)d_in[4];
  const float* bih = (const float*)d_in[5];
  const float* bhh = (const float*)d_in[6];
  const float* c1w = (const float*)d_in[7];
  const float* c1b = (const float*)d_in[8];
  const float* bn1g = (const float*)d_in[9];
  const float* bn1b = (const float*)d_in[10];
  const float* c2w = (const float*)d_in[11];
  const float* c2b = (const float*)d_in[12];
  const float* bn2g = (const float*)d_in[13];
  const float* bn2b = (const float*)d_in[14];
  const float* c3w = (const float*)d_in[15];
  const float* c3b = (const float*)d_in[16];
  const float* bn3g = (const float*)d_in[17];
  const float* bn3b = (const float*)d_in[18];
  const float* c4w = (const float*)d_in[19];
  const float* c4b = (const float*)d_in[20];
  const float* bn4g = (const float*)d_in[21];
  const float* bn4b = (const float*)d_in[22];
  const float* g1w = (const float*)d_in[23];
  const float* g1b = (const float*)d_in[24];
  const float* g2w = (const float*)d_in[25];
  const float* g2b = (const float*)d_in[26];
  const float* g3w = (const float*)d_in[27];
  const float* g3b = (const float*)d_in[28];
  const float* g4w = (const float*)d_in[29];
  const float* g4b = (const float*)d_in[30];
  const float* f1w = (const float*)d_in[31];
  const float* f1b = (const float*)d_in[32];
  const float* f2w = (const float*)d_in[33];
  const float* f2b = (const float*)d_in[34];
  const float* f3w = (const float*)d_in[35];
  const float* f3b = (const float*)d_in[36];
  float* out = (float*)d_out;

  float* wsf = (float*)d_ws;
  float* arenaA = wsf;                                // 6,291,456 f (y1/y3; later xpart)
  float* arenaB = wsf + 6291456;                      // 1,572,864 f (y2/y4)
  float* qvec   = wsf + 8519680;                      // 8,192 f
  float* pre_i  = wsf + 8527872;                      // 1,048,576 f
  float* pre_j  = wsf + 9576448;                      // 1,048,576 f
  float* pre_q  = wsf + 10625024;                     // 16,384 f
  float* stats  = wsf + 10657792;                     // 256 f (4 layers x 24 x 2)
  unsigned short* wbf = (unsigned short*)(wsf + 10658048); // 196,608 bf16 (16B aligned)
  float* xpart  = arenaA;                             // reuse: convs done before rel_k

  hipMemsetAsync(stats, 0, 256 * sizeof(float), stream);

  wprep_k<<<768, 256, 0, stream>>>(g2w, g3w, g4w, wbf);
  lstm_k<<<64, 512, 0, stream>>>(question, emb, wih, bih, bhh, whh, qvec);

  conv_k<3, 128><<<24576, 256, 0, stream>>>(image, c1w, c1b, arenaA);
  stats_k<<<24 * 16, 256, 0, stream>>>(arenaA, stats + 0, 4096, 16);
  bn_k<<<24576, 256, 0, stream>>>(arenaA, stats + 0, bn1g, bn1b, 4096, 1.0f / 262144.0f);

  conv_k<24, 64><<<6144, 256, 0, stream>>>(arenaA, c2w, c2b, arenaB);
  stats_k<<<24 * 16, 256, 0, stream>>>(arenaB, stats + 48, 1024, 16);
  bn_k<<<6144, 256, 0, stream>>>(arenaB, stats + 48, bn2g, bn2b, 1024, 1.0f / 65536.0f);

  conv_k<24, 32><<<1536, 256, 0, stream>>>(arenaB, c3w, c3b, arenaA);
  stats_k<<<24 * 4, 256, 0, stream>>>(arenaA, stats + 96, 256, 4);
  bn_k<<<1536, 256, 0, stream>>>(arenaA, stats + 96, bn3g, bn3b, 256, 1.0f / 16384.0f);

  conv_k<24, 16><<<384, 256, 0, stream>>>(arenaA, c4w, c4b, arenaB);
  stats_k<<<24, 256, 0, stream>>>(arenaB, stats + 144, 64, 1);

  pre_k<<<4096 + 64, 256, 0, stream>>>(arenaB, stats + 144, bn4g, bn4b, g1w, g1b, qvec,
                                       pre_i, pre_j, pre_q);

  rel_k<<<4096, 256, 0, stream>>>(pre_i, pre_j, pre_q, wbf, g2b, g3b, g4b, xpart);

  final_k<<<64, 256, 0, stream>>>(xpart, f1w, f1b, f2w, f2b, f3w, f3b, out);
}